// Round 16
// baseline (173.777 us; speedup 1.0000x reference)
//
#include <hip/hip_runtime.h>
#include <cmath>

#define B_ 8
#define N_ 4096
#define D_ 512
#define M_ 512
#define EPS_ 1e-5f
#define DT_ 0.25f

typedef unsigned short u16;
typedef unsigned int u32;
typedef __attribute__((ext_vector_type(8))) u16 u16x8;
typedef __attribute__((ext_vector_type(4))) u16 u16x4;
typedef __attribute__((ext_vector_type(8))) short bf16x8;
typedef __attribute__((ext_vector_type(4))) float f32x4;

__device__ __forceinline__ float bf2f(u16 h) {
    return __builtin_bit_cast(float, (u32)h << 16);
}
// hardware packed fp32->bf16 (gfx950 v_cvt_pk_bf16_f32, RNE) [T12 recipe]
__device__ __forceinline__ u32 cvtpk(float lo, float hi) {
    u32 r;
    asm("v_cvt_pk_bf16_f32 %0, %1, %2" : "=v"(r) : "v"(lo), "v"(hi));
    return r;
}
__device__ __forceinline__ u16 f2bf(float f) { return (u16)cvtpk(f, 0.f); }
__device__ __forceinline__ u16x8 pack8(float4 a, float4 b) {
    union { u32 w[4]; u16x8 o; } u;
    u.w[0] = cvtpk(a.x, a.y); u.w[1] = cvtpk(a.z, a.w);
    u.w[2] = cvtpk(b.x, b.y); u.w[3] = cvtpk(b.z, b.w);
    return u.o;
}

// async global->LDS, 16B per lane; lds must be wave-uniform base (+lane*16 HW)
__device__ __forceinline__ void gload16(const void* g, void* l) {
    __builtin_amdgcn_global_load_lds(
        (const __attribute__((address_space(1))) void*)g,
        (__attribute__((address_space(3))) void*)l, 16, 0, 0);
}

// ---------------------------------------------------------------------------
// Transpose + fp32->bf16: src [Z][R][C] -> dst [Z][C][R]
// ---------------------------------------------------------------------------
__global__ __launch_bounds__(256)
void k_prep_T(const float* __restrict__ src, u16* __restrict__ dst, int R, int C)
{
    __shared__ float tile[64][65];
    const int t = threadIdx.x;
    const int c0 = blockIdx.x * 64;
    const int r0 = blockIdx.y * 64;
    const int z  = blockIdx.z;
    const float* s = src + (size_t)z * R * C;
    u16* d = dst + (size_t)z * R * C;
    const int rl = t >> 4, cc = (t & 15) * 4;
#pragma unroll
    for (int i = 0; i < 4; ++i) {
        float4 v = *reinterpret_cast<const float4*>(s + (size_t)(r0 + rl + i * 16) * C + c0 + cc);
        tile[rl + i * 16][cc + 0] = v.x;
        tile[rl + i * 16][cc + 1] = v.y;
        tile[rl + i * 16][cc + 2] = v.z;
        tile[rl + i * 16][cc + 3] = v.w;
    }
    __syncthreads();
#pragma unroll
    for (int i = 0; i < 2; ++i) {
        int q = t + i * 256;
        int cl = q >> 3, rc = (q & 7) * 8;
        float4 va, vb;
        va.x = tile[rc + 0][cl]; va.y = tile[rc + 1][cl];
        va.z = tile[rc + 2][cl]; va.w = tile[rc + 3][cl];
        vb.x = tile[rc + 4][cl]; vb.y = tile[rc + 5][cl];
        vb.z = tile[rc + 6][cl]; vb.w = tile[rc + 7][cl];
        *reinterpret_cast<u16x8*>(d + (size_t)(c0 + cl) * R + r0 + rc) = pack8(va, vb);
    }
}

// ---------------------------------------------------------------------------
// Projection GEMM, fused RBF A-tile (hw cvt_pk), tile 64x128, 24KB LDS,
// 4 blocks/CU, grid 1024 XCD-grouped. NO ATOMICS: each K-chunk writes its
// partial to part[kc][b][m][d] with plain coalesced stores; k_sum reduces.
// ---------------------------------------------------------------------------
__global__ __launch_bounds__(512, 4)
void k_projgemm(const float* __restrict__ pos, const float* __restrict__ gp,
                const float* __restrict__ log_sigma, const u16* __restrict__ xT,
                float* __restrict__ part)
{
    extern __shared__ u16 smem[];            // 24 KB
    u16* As = smem;                          // [64][64] kern tile (8 KB)
    u16* Bs = smem + 64 * 64;                // [128][64] xT rows (16 KB)

    const int t = threadIdx.x;
    // XCD-aware decode: all 32 blocks of a (b,chunk) group share d%8.
    const int d = blockIdx.x;                // 0..1023
    const int xcd = d & 7;
    const int q = d >> 3;                    // 0..127
    const int w = q & 31;                    // within-group: mtile + ntile
    const int mtile = w & 7;
    const int ntile = w >> 3;                // 0..3
    const int gq = q >> 5;                   // 0..3
    const int g = gq * 8 + xcd;              // group id 0..31
    const int b = g & 7;
    const int kc = g >> 3;                   // K-chunk 0..3
    const int m0 = mtile * 64;
    const int cb0 = ntile * 128;             // output col base
    const int nc0 = kc * 1024;               // K-chunk base

    const int l = t & 63, wid = t >> 6;
    const int wm = wid >> 2, wn = wid & 3;

    f32x4 acc[2][2];
#pragma unroll
    for (int i = 0; i < 2; ++i)
#pragma unroll
        for (int j = 0; j < 2; ++j) acc[i][j] = (f32x4){0.f, 0.f, 0.f, 0.f};

    // A-tile generation: thread owns (row=t>>3, LDS chunk=t&7) for global
    // n-chunk gch = sch ^ (row&7) (src-pre-swizzle).
    const int a_row = t >> 3, a_sch = t & 7;
    const int a_gch = a_sch ^ (a_row & 7);
    const float gm = gp[(size_t)b * M_ + m0 + a_row];
    const float sigma = __expf(log_sigma[0]);
    const float ninv2s2 = -0.5f / (sigma * sigma);
    const float* pb = pos + (size_t)b * N_ + nc0 + a_gch * 8;
    u16* a_wr = As + a_row * 64 + a_sch * 8;

    const u16* xb = xT + ((size_t)b * D_ + cb0) * N_ + nc0;

    const int fr = l & 15, fj = l >> 4;

    for (int ks = 0; ks < 16; ++ks) {
        const int kk = ks * 64;
        __syncthreads();                     // prev compute done
        // B stage: 128 rows x 64 k = 1024 chunks, 2/thread (async)
#pragma unroll
        for (int i = 0; i < 2; ++i) {
            const int cid = t + i * 512;
            const int brow = cid >> 3, bsch = cid & 7;
            gload16(xb + (size_t)brow * N_ + kk + ((bsch ^ (brow & 7)) * 8),
                    Bs + (size_t)wid * 512 + i * 4096);
        }
        // A compute: 8 RBF weights (hw cvt_pk), overlaps B flight
        {
            float4 p0 = *reinterpret_cast<const float4*>(pb + kk);
            float4 p1 = *reinterpret_cast<const float4*>(pb + kk + 4);
            float4 ea, eb;
            float d0 = gm - p0.x, d1 = gm - p0.y, d2 = gm - p0.z, d3 = gm - p0.w;
            float d4 = gm - p1.x, d5 = gm - p1.y, d6 = gm - p1.z, d7 = gm - p1.w;
            ea.x = __expf(d0 * d0 * ninv2s2); ea.y = __expf(d1 * d1 * ninv2s2);
            ea.z = __expf(d2 * d2 * ninv2s2); ea.w = __expf(d3 * d3 * ninv2s2);
            eb.x = __expf(d4 * d4 * ninv2s2); eb.y = __expf(d5 * d5 * ninv2s2);
            eb.z = __expf(d6 * d6 * ninv2s2); eb.w = __expf(d7 * d7 * ninv2s2);
            *reinterpret_cast<u16x8*>(a_wr) = pack8(ea, eb);
        }
        __syncthreads();                     // B landed + A ds_writes visible

#pragma unroll
        for (int kl = 0; kl < 2; ++kl) {
            const int cbase = kl * 4 + fj;
            const int ar0 = wm * 32 + fr, ar1 = ar0 + 16;
            bf16x8 a0 = *reinterpret_cast<const bf16x8*>(
                As + ar0 * 64 + ((cbase ^ (ar0 & 7)) * 8));
            bf16x8 a1 = *reinterpret_cast<const bf16x8*>(
                As + ar1 * 64 + ((cbase ^ (ar1 & 7)) * 8));
#pragma unroll
            for (int nf = 0; nf < 2; ++nf) {
                const int bcol = wn * 32 + nf * 16 + fr;
                bf16x8 bw = *reinterpret_cast<const bf16x8*>(
                    Bs + bcol * 64 + ((cbase ^ (bcol & 7)) * 8));
                acc[0][nf] = __builtin_amdgcn_mfma_f32_16x16x32_bf16(a0, bw, acc[0][nf], 0, 0, 0);
                acc[1][nf] = __builtin_amdgcn_mfma_f32_16x16x32_bf16(a1, bw, acc[1][nf], 0, 0, 0);
            }
        }
    }

    // plain coalesced stores of this K-chunk's partial (no RMW, no memset)
    float* pb_out = part + ((size_t)(kc * B_ + b) * M_) * D_;
#pragma unroll
    for (int mf = 0; mf < 2; ++mf)
#pragma unroll
        for (int nf = 0; nf < 2; ++nf) {
            const int col = cb0 + wn * 32 + nf * 16 + fr;
#pragma unroll
            for (int r = 0; r < 4; ++r) {
                const int m = m0 + wm * 32 + mf * 16 + fj * 4 + r;
                pb_out[(size_t)m * D_ + col] = acc[mf][nf][r];
            }
        }
}

// ---------------------------------------------------------------------------
// Partial reduction: field = part0 + part1 + part2 + part3. 32MB -> 8MB.
// ---------------------------------------------------------------------------
__global__ __launch_bounds__(256)
void k_sum(const float* __restrict__ part, float* __restrict__ field)
{
    const size_t i = ((size_t)blockIdx.x * 256 + threadIdx.x) * 4;
    const size_t S = (size_t)B_ * M_ * D_;
    float4 v0 = *reinterpret_cast<const float4*>(part + i);
    float4 v1 = *reinterpret_cast<const float4*>(part + S + i);
    float4 v2 = *reinterpret_cast<const float4*>(part + 2 * S + i);
    float4 v3 = *reinterpret_cast<const float4*>(part + 3 * S + i);
    float4 o;
    o.x = (v0.x + v1.x) + (v2.x + v3.x);
    o.y = (v0.y + v1.y) + (v2.y + v3.y);
    o.z = (v0.z + v1.z) + (v2.z + v3.z);
    o.w = (v0.w + v1.w) + (v2.w + v3.w);
    *reinterpret_cast<float4*>(field + i) = o;
}

// ---------------------------------------------------------------------------
// Diffusion step: fout = fin + dt*(alpha*lap + tanh(fin @ Wi + bi)).
// Col-split 128: grid (M/16, D/128, B) = 1024 blocks, 33KB LDS -> 4 blocks/CU.
// WiT B-tiles via global_load_lds (BK=64, 8 steps, chunk^(row&7) pre-swizzle).
// fs (A, full-K) resident; Cs aliases Bs post-GEMM.
// ---------------------------------------------------------------------------
__global__ __launch_bounds__(256, 4)
void k_diffuse(const float* __restrict__ fin, const u16* __restrict__ WiT,
               const float* __restrict__ bi, const float* __restrict__ alpha_p,
               float* __restrict__ fout)
{
    extern __shared__ u16 dsm[];     // 33024 B
    u16* fs = dsm;                   // [16][520] bf16 field rows (16.6 KB)
    u16* Bs = dsm + 16 * 520;        // [128][64] WiT tile (16 KB)
    float* Cs = (float*)Bs;          // [16][132] fp32, aliases Bs post-GEMM

    const int t = threadIdx.x;
    const int m0 = blockIdx.x * 16;
    const int cb0 = blockIdx.y * 128;
    const int b = blockIdx.z;
    const int l = t & 63, wn = t >> 6;
    const int fr = l & 15, fj = l >> 4;
    const float* fb = fin + (size_t)b * M_ * D_;

    {   // stage fs: 16 rows x 512 cols fp32 -> bf16 (hw cvt)
        const int row = t >> 4, ch = (t & 15) * 32;
        const float* src = fb + (size_t)(m0 + row) * D_ + ch;
#pragma unroll
        for (int j = 0; j < 4; ++j) {
            float4 v0 = *reinterpret_cast<const float4*>(src + j * 8);
            float4 v1 = *reinterpret_cast<const float4*>(src + j * 8 + 4);
            *reinterpret_cast<u16x8*>(fs + row * 520 + ch + j * 8) = pack8(v0, v1);
        }
    }

    f32x4 acc[2];
#pragma unroll
    for (int i = 0; i < 2; ++i) acc[i] = (f32x4){0.f, 0.f, 0.f, 0.f};

    const u16* wb = WiT + (size_t)cb0 * D_;

    for (int ks = 0; ks < 8; ++ks) {
        const int kk = ks * 64;
        __syncthreads();                 // iter0: fs writes flushed; else: prev Bs reads done
        // stage B: 128 rows (Wi output-cols) x 64 k, 1024 chunks, 4/thread
#pragma unroll
        for (int i = 0; i < 4; ++i) {
            const int cid = t + i * 256;
            const int brow = cid >> 3, bsch = cid & 7;
            gload16(wb + (size_t)brow * D_ + kk + ((bsch ^ (brow & 7)) * 8),
                    Bs + (i * 256 + wn * 64) * 8);
        }
        __syncthreads();                 // loads landed

#pragma unroll
        for (int kl = 0; kl < 2; ++kl) {
            const int cbase = kl * 4 + fj;
            bf16x8 a = *reinterpret_cast<const bf16x8*>(
                fs + fr * 520 + kk + kl * 32 + fj * 8);
#pragma unroll
            for (int nf = 0; nf < 2; ++nf) {
                const int bcol = wn * 32 + nf * 16 + fr;
                bf16x8 bw = *reinterpret_cast<const bf16x8*>(
                    Bs + bcol * 64 + ((cbase ^ (bcol & 7)) * 8));
                acc[nf] = __builtin_amdgcn_mfma_f32_16x16x32_bf16(a, bw, acc[nf], 0, 0, 0);
            }
        }
    }

    __syncthreads();   // all Bs reads done before Cs (alias) overwrite
    // stage gemm+bias into Cs (scatter, stride 132)
#pragma unroll
    for (int nf = 0; nf < 2; ++nf) {
        const int cl = wn * 32 + nf * 16 + fr;
        const float bic = bi[cb0 + cl];
#pragma unroll
        for (int r = 0; r < 4; ++r)
            Cs[(fj * 4 + r) * 132 + cl] = acc[nf][r] + bic;
    }
    __syncthreads();

    // row pass: wave wn owns rows wn*4..+3, float2 per lane (128 cols)
    const float al = alpha_p[0];
    float* fob = fout + (size_t)b * M_ * D_;
#pragma unroll
    for (int i = 0; i < 4; ++i) {
        const int row = wn * 4 + i;
        const int m = m0 + row;
        const int mu_ = m > 0 ? m - 1 : 0;
        const int md = m < M_ - 1 ? m + 1 : M_ - 1;
        const int cl = cb0 + l * 2;
        float2 g  = *reinterpret_cast<const float2*>(&Cs[row * 132 + l * 2]);
        float2 fc = *reinterpret_cast<const float2*>(fb + (size_t)m * D_ + cl);
        float2 fu = *reinterpret_cast<const float2*>(fb + (size_t)mu_ * D_ + cl);
        float2 fd = *reinterpret_cast<const float2*>(fb + (size_t)md * D_ + cl);
        float2 o;
        o.x = fc.x + DT_ * (al * (fu.x + fd.x - 2.f * fc.x) + tanhf(g.x));
        o.y = fc.y + DT_ * (al * (fu.y + fd.y - 2.f * fc.y) + tanhf(g.y));
        *reinterpret_cast<float2*>(fob + (size_t)m * D_ + cl) = o;
    }
}

// ---------------------------------------------------------------------------
// Tail part 1: enh = LN1(lerp(field) + x) -> bf16.
// ---------------------------------------------------------------------------
__global__ __launch_bounds__(256)
void k_enh(const float* __restrict__ x, const float* __restrict__ pos,
           const float* __restrict__ field, const float* __restrict__ g1,
           const float* __restrict__ b1, u16* __restrict__ enh)
{
    const int t = threadIdx.x;
    const int wid = t >> 6, l = t & 63;
    const int n = blockIdx.x * 4 + wid;
    const int b = blockIdx.y;
    const int c = l * 8;

    const float* xr = x + ((size_t)b * N_ + n) * D_ + c;
    float4 xa = *reinterpret_cast<const float4*>(xr);
    float4 xb = *reinterpret_cast<const float4*>(xr + 4);
    const float p = pos[(size_t)b * N_ + n];
    float u = p * (float)(M_ - 1);
    int i0 = (int)floorf(u);
    i0 = i0 < 0 ? 0 : (i0 > M_ - 2 ? M_ - 2 : i0);
    const float w = u - (float)i0;
    const float* fp0 = field + ((size_t)b * M_ + i0) * D_ + c;
    float4 f0a = *reinterpret_cast<const float4*>(fp0);
    float4 f0b = *reinterpret_cast<const float4*>(fp0 + 4);
    float4 f1a = *reinterpret_cast<const float4*>(fp0 + D_);
    float4 f1b = *reinterpret_cast<const float4*>(fp0 + D_ + 4);

    float s[8];
    s[0] = f0a.x + w * (f1a.x - f0a.x) + xa.x;
    s[1] = f0a.y + w * (f1a.y - f0a.y) + xa.y;
    s[2] = f0a.z + w * (f1a.z - f0a.z) + xa.z;
    s[3] = f0a.w + w * (f1a.w - f0a.w) + xa.w;
    s[4] = f0b.x + w * (f1b.x - f0b.x) + xb.x;
    s[5] = f0b.y + w * (f1b.y - f0b.y) + xb.y;
    s[6] = f0b.z + w * (f1b.z - f0b.z) + xb.z;
    s[7] = f0b.w + w * (f1b.w - f0b.w) + xb.w;

    float sum = 0.f, ss = 0.f;
#pragma unroll
    for (int j = 0; j < 8; ++j) { sum += s[j]; ss += s[j] * s[j]; }
#pragma unroll
    for (int off = 1; off <= 32; off <<= 1) {
        sum += __shfl_xor(sum, off);
        ss  += __shfl_xor(ss, off);
    }
    const float mu = sum * (1.f / 512.f);
    const float rs = rsqrtf(ss * (1.f / 512.f) - mu * mu + EPS_);

    float4 ga = *reinterpret_cast<const float4*>(g1 + c);
    float4 gb = *reinterpret_cast<const float4*>(g1 + c + 4);
    float4 ba = *reinterpret_cast<const float4*>(b1 + c);
    float4 bb = *reinterpret_cast<const float4*>(b1 + c + 4);
    float4 ea, eb;
    ea.x = (s[0] - mu) * rs * ga.x + ba.x;
    ea.y = (s[1] - mu) * rs * ga.y + ba.y;
    ea.z = (s[2] - mu) * rs * ga.z + ba.z;
    ea.w = (s[3] - mu) * rs * ga.w + ba.w;
    eb.x = (s[4] - mu) * rs * gb.x + bb.x;
    eb.y = (s[5] - mu) * rs * gb.y + bb.y;
    eb.z = (s[6] - mu) * rs * gb.z + bb.z;
    eb.w = (s[7] - mu) * rs * gb.w + bb.w;
    *reinterpret_cast<u16x8*>(enh + ((size_t)b * N_ + n) * D_ + c) = pack8(ea, eb);
}

// ---------------------------------------------------------------------------
// Tail part 2 (round-14 known-good): out = LN2(enh @ WoT + bo + enh).
// Single-buffer BK=64, 72KB dyn LDS, Cs[32][516] 2-pass epilogue.
// ---------------------------------------------------------------------------
__global__ __launch_bounds__(512, 4)
void k_gemm_ln(const u16* __restrict__ enh, const u16* __restrict__ WoT,
               const float* __restrict__ bo, const float* __restrict__ g2,
               const float* __restrict__ b2, float* __restrict__ out)
{
    extern __shared__ u16 smem[];            // 72 KB
    u16* As = smem;                          // [64][64] linear+src-swz (8 KB)
    u16* Bs = smem + 64 * 64;                // [512][64] linear+src-swz (64 KB)
    float* Cs = (float*)smem;                // [32][516] fp32, reused post-GEMM

    const int t = threadIdx.x;
    const int r0 = blockIdx.x * 64;          // row in flattened [B*N][D]
    const int l = t & 63, wid = t >> 6;
    const int wm = wid >> 2, wn = wid & 3;

    f32x4 acc[2][8];
#pragma unroll
    for (int i = 0; i < 2; ++i)
#pragma unroll
        for (int j = 0; j < 8; ++j) acc[i][j] = (f32x4){0.f, 0.f, 0.f, 0.f};

    // staging assignments (chunk = 8 bf16 = 16B)
    const int a_row = t >> 3, a_sch = t & 7;                  // A: 512 chunks
    const u16* a_src = enh + (size_t)(r0 + a_row) * D_ + (a_sch ^ (a_row & 7)) * 8;
    u16* a_dst = As + (size_t)wid * 512;                      // wave-uniform base

    const int fr = l & 15, fj = l >> 4;                       // frag coords

    for (int ks = 0; ks < 8; ++ks) {
        const int kk = ks * 64;
        __syncthreads();                     // prev compute done (tiles reusable)
        gload16(a_src + kk, a_dst);
#pragma unroll
        for (int i = 0; i < 8; ++i) {
            const int cid = t + i * 512;                      // B chunk id
            const int brow = cid >> 3, bsch = cid & 7;
            gload16(WoT + (size_t)brow * D_ + kk + ((bsch ^ (brow & 7)) * 8),
                    Bs + (size_t)wid * 512 + i * 4096);
        }
        __syncthreads();                     // loads landed (vmcnt0 at barrier)

#pragma unroll
        for (int kl = 0; kl < 2; ++kl) {     // two k-halves of 32
            const int cbase = kl * 4 + fj;   // chunk index 0..7
            const int ar0 = wm * 32 + fr, ar1 = ar0 + 16;
            bf16x8 a0 = *reinterpret_cast<const bf16x8*>(
                As + ar0 * 64 + ((cbase ^ (ar0 & 7)) * 8));
            bf16x8 a1 = *reinterpret_cast<const bf16x8*>(
                As + ar1 * 64 + ((cbase ^ (ar1 & 7)) * 8));
#pragma unroll
            for (int nf = 0; nf < 8; ++nf) {
                const int bcol = wn * 128 + nf * 16 + fr;
                bf16x8 bw = *reinterpret_cast<const bf16x8*>(
                    Bs + bcol * 64 + ((cbase ^ (bcol & 7)) * 8));
                acc[0][nf] = __builtin_amdgcn_mfma_f32_16x16x32_bf16(a0, bw, acc[0][nf], 0, 0, 0);
                acc[1][nf] = __builtin_amdgcn_mfma_f32_16x16x32_bf16(a1, bw, acc[1][nf], 0, 0, 0);
            }
        }
    }

#pragma unroll
    for (int mf = 0; mf < 2; ++mf) {
        __syncthreads();   // pass separation (protects Cs reuse vs B reads / prev pass)
        // scatter acc + bias into Cs; localrow = wm*16 + (l>>4)*4 + r
#pragma unroll
        for (int nf = 0; nf < 8; ++nf) {
            const int col = wn * 128 + nf * 16 + fr;
            const float boc = bo[col];
#pragma unroll
            for (int r = 0; r < 4; ++r)
                Cs[(wm * 16 + fj * 4 + r) * 516 + col] = acc[mf][nf][r] + boc;
        }
        __syncthreads();
        // row pass: wave wid owns localrows wid*4..+3; cols {l*4, 256+l*4}
#pragma unroll
        for (int i = 0; i < 4; ++i) {
            const int lr = wid * 4 + i;
            const int grow = r0 + (lr >> 4) * 32 + mf * 16 + (lr & 15);
            const int c1 = l * 4, c2 = 256 + l * 4;
            float4 fa = *reinterpret_cast<const float4*>(&Cs[lr * 516 + c1]);
            float4 fb4 = *reinterpret_cast<const float4*>(&Cs[lr * 516 + c2]);
            u16x4 e1 = *reinterpret_cast<const u16x4*>(enh + (size_t)grow * D_ + c1);
            u16x4 e2 = *reinterpret_cast<const u16x4*>(enh + (size_t)grow * D_ + c2);
            float v[8];
            v[0] = fa.x + bf2f(e1[0]); v[1] = fa.y + bf2f(e1[1]);
            v[2] = fa.z + bf2f(e1[2]); v[3] = fa.w + bf2f(e1[3]);
            v[4] = fb4.x + bf2f(e2[0]); v[5] = fb4.y + bf2f(e2[1]);
            v[6] = fb4.z + bf2f(e2[2]); v[7] = fb4.w + bf2f(e2[3]);

            float sum = 0.f, ss = 0.f;
#pragma unroll
            for (int j = 0; j < 8; ++j) { sum += v[j]; ss += v[j] * v[j]; }
#pragma unroll
            for (int off = 1; off <= 32; off <<= 1) {
                sum += __shfl_xor(sum, off);
                ss  += __shfl_xor(ss, off);
            }
            const float mu = sum * (1.f / 512.f);
            const float rs = rsqrtf(ss * (1.f / 512.f) - mu * mu + EPS_);

            float4 ga = *reinterpret_cast<const float4*>(g2 + c1);
            float4 gb = *reinterpret_cast<const float4*>(g2 + c2);
            float4 ba = *reinterpret_cast<const float4*>(b2 + c1);
            float4 bb = *reinterpret_cast<const float4*>(b2 + c2);
            float4 oa, ob;
            oa.x = (v[0] - mu) * rs * ga.x + ba.x;
            oa.y = (v[1] - mu) * rs * ga.y + ba.y;
            oa.z = (v[2] - mu) * rs * ga.z + ba.z;
            oa.w = (v[3] - mu) * rs * ga.w + ba.w;
            ob.x = (v[4] - mu) * rs * gb.x + bb.x;
            ob.y = (v[5] - mu) * rs * gb.y + bb.y;
            ob.z = (v[6] - mu) * rs * gb.z + bb.z;
            ob.w = (v[7] - mu) * rs * gb.w + bb.w;
            float* orow = out + (size_t)grow * D_;
            *reinterpret_cast<float4*>(orow + c1) = oa;
            *reinterpret_cast<float4*>(orow + c2) = ob;
        }
    }
}

extern "C" void kernel_launch(void* const* d_in, const int* in_sizes, int n_in,
                              void* d_out, int out_size, void* d_ws, size_t ws_size,
                              hipStream_t stream) {
    (void)in_sizes; (void)n_in; (void)out_size; (void)ws_size;
    const float* x   = (const float*)d_in[0];
    const float* pos = (const float*)d_in[1];
    const float* gp  = (const float*)d_in[2];
    const float* ls  = (const float*)d_in[3];
    const float* al  = (const float*)d_in[4];
    const float* Wi  = (const float*)d_in[5];
    const float* bi  = (const float*)d_in[6];
    const float* g1  = (const float*)d_in[7];
    const float* b1  = (const float*)d_in[8];
    const float* Wo  = (const float*)d_in[9];
    const float* bo  = (const float*)d_in[10];
    const float* g2  = (const float*)d_in[11];
    const float* b2  = (const float*)d_in[12];
    float* out = (float*)d_out;

    float* f0 = (float*)d_ws;                              // 8 MB fp32 field
    float* f1 = f0 + (size_t)B_ * M_ * D_;                 // 8 MB ping-pong
    u16* xT  = (u16*)(f1 + (size_t)B_ * M_ * D_);          // 32 MB bf16 x^T
    u16* WiT = xT + (size_t)B_ * D_ * N_;                  // 512 KB
    u16* WoT = WiT + (size_t)D_ * D_;                      // 512 KB
    u16* enh = xT;                                         // alias: xT dead after project
    float* part = (float*)d_out;                           // 32 MB partials in d_out
                                                           // (dead before k_gemm_ln writes)

    const int smGemm = 64 * 64 * 2 + 512 * 64 * 2;         // 73728 B (k_gemm_ln)
    const int smProj = 64 * 64 * 2 + 128 * 64 * 2;         // 24576 B (k_projgemm)
    const int smDiff = 16 * 520 * 2 + 128 * 64 * 2;        // 33024 B (k_diffuse)
    hipFuncSetAttribute(reinterpret_cast<const void*>(k_gemm_ln),
                        hipFuncAttributeMaxDynamicSharedMemorySize, smGemm);
    hipFuncSetAttribute(reinterpret_cast<const void*>(k_projgemm),
                        hipFuncAttributeMaxDynamicSharedMemorySize, smProj);
    hipFuncSetAttribute(reinterpret_cast<const void*>(k_diffuse),
                        hipFuncAttributeMaxDynamicSharedMemorySize, smDiff);

    k_prep_T<<<dim3(D_ / 64, N_ / 64, B_), 256, 0, stream>>>(x, xT, N_, D_);
    k_prep_T<<<dim3(D_ / 64, D_ / 64, 1), 256, 0, stream>>>(Wi, WiT, D_, D_);
    k_prep_T<<<dim3(D_ / 64, D_ / 64, 1), 256, 0, stream>>>(Wo, WoT, D_, D_);
    k_projgemm<<<dim3(1024), 512, smProj, stream>>>(pos, gp, ls, xT, part);
    k_sum<<<dim3((B_ * M_ * D_) / (256 * 4)), 256, 0, stream>>>(part, f0);
    k_diffuse<<<dim3(M_ / 16, D_ / 128, B_), 256, smDiff, stream>>>(f0, WiT, bi, al, f1);
    k_diffuse<<<dim3(M_ / 16, D_ / 128, B_), 256, smDiff, stream>>>(f1, WiT, bi, al, f0);
    k_diffuse<<<dim3(M_ / 16, D_ / 128, B_), 256, smDiff, stream>>>(f0, WiT, bi, al, f1);
    k_diffuse<<<dim3(M_ / 16, D_ / 128, B_), 256, smDiff, stream>>>(f1, WiT, bi, al, f0);
    k_enh<<<dim3(N_ / 4, B_), 256, 0, stream>>>(x, pos, f0, g1, b1, enh);
    k_gemm_ln<<<dim3(B_ * N_ / 64), 512, smGemm, stream>>>(enh, WoT, bo, g2, b2, out);
}

// Round 17
// 171.442 us; speedup vs baseline: 1.0136x; 1.0136x over previous
//
#include <hip/hip_runtime.h>
#include <cmath>

#define B_ 8
#define N_ 4096
#define D_ 512
#define M_ 512
#define EPS_ 1e-5f
#define DT_ 0.25f

typedef unsigned short u16;
typedef unsigned int u32;
typedef __attribute__((ext_vector_type(8))) u16 u16x8;
typedef __attribute__((ext_vector_type(4))) u16 u16x4;
typedef __attribute__((ext_vector_type(8))) short bf16x8;
typedef __attribute__((ext_vector_type(4))) float f32x4;

__device__ __forceinline__ float bf2f(u16 h) {
    return __builtin_bit_cast(float, (u32)h << 16);
}
// hardware packed fp32->bf16 (gfx950 v_cvt_pk_bf16_f32, RNE) [T12 recipe]
__device__ __forceinline__ u32 cvtpk(float lo, float hi) {
    u32 r;
    asm("v_cvt_pk_bf16_f32 %0, %1, %2" : "=v"(r) : "v"(lo), "v"(hi));
    return r;
}
__device__ __forceinline__ u16 f2bf(float f) { return (u16)cvtpk(f, 0.f); }
__device__ __forceinline__ u16x8 pack8(float4 a, float4 b) {
    union { u32 w[4]; u16x8 o; } u;
    u.w[0] = cvtpk(a.x, a.y); u.w[1] = cvtpk(a.z, a.w);
    u.w[2] = cvtpk(b.x, b.y); u.w[3] = cvtpk(b.z, b.w);
    return u.o;
}

// async global->LDS, 16B per lane; lds must be wave-uniform base (+lane*16 HW)
__device__ __forceinline__ void gload16(const void* g, void* l) {
    __builtin_amdgcn_global_load_lds(
        (const __attribute__((address_space(1))) void*)g,
        (__attribute__((address_space(3))) void*)l, 16, 0, 0);
}

// ---------------------------------------------------------------------------
// Transpose + fp32->bf16: src [Z][R][C] -> dst [Z][C][R]
// ---------------------------------------------------------------------------
__global__ __launch_bounds__(256)
void k_prep_T(const float* __restrict__ src, u16* __restrict__ dst, int R, int C)
{
    __shared__ float tile[64][65];
    const int t = threadIdx.x;
    const int c0 = blockIdx.x * 64;
    const int r0 = blockIdx.y * 64;
    const int z  = blockIdx.z;
    const float* s = src + (size_t)z * R * C;
    u16* d = dst + (size_t)z * R * C;
    const int rl = t >> 4, cc = (t & 15) * 4;
#pragma unroll
    for (int i = 0; i < 4; ++i) {
        float4 v = *reinterpret_cast<const float4*>(s + (size_t)(r0 + rl + i * 16) * C + c0 + cc);
        tile[rl + i * 16][cc + 0] = v.x;
        tile[rl + i * 16][cc + 1] = v.y;
        tile[rl + i * 16][cc + 2] = v.z;
        tile[rl + i * 16][cc + 3] = v.w;
    }
    __syncthreads();
#pragma unroll
    for (int i = 0; i < 2; ++i) {
        int q = t + i * 256;
        int cl = q >> 3, rc = (q & 7) * 8;
        float4 va, vb;
        va.x = tile[rc + 0][cl]; va.y = tile[rc + 1][cl];
        va.z = tile[rc + 2][cl]; va.w = tile[rc + 3][cl];
        vb.x = tile[rc + 4][cl]; vb.y = tile[rc + 5][cl];
        vb.z = tile[rc + 6][cl]; vb.w = tile[rc + 7][cl];
        *reinterpret_cast<u16x8*>(d + (size_t)(c0 + cl) * R + r0 + rc) = pack8(va, vb);
    }
}

// ---------------------------------------------------------------------------
// Projection GEMM, fused RBF A-tile (hw cvt_pk), tile 64x128, 24KB LDS,
// 4 blocks/CU, grid 1024 XCD-grouped. NO ATOMICS: each K-chunk writes its
// partial to part[kc][b][m][d] with plain coalesced stores; k_sum reduces.
// ---------------------------------------------------------------------------
__global__ __launch_bounds__(512, 4)
void k_projgemm(const float* __restrict__ pos, const float* __restrict__ gp,
                const float* __restrict__ log_sigma, const u16* __restrict__ xT,
                float* __restrict__ part)
{
    extern __shared__ u16 smem[];            // 24 KB
    u16* As = smem;                          // [64][64] kern tile (8 KB)
    u16* Bs = smem + 64 * 64;                // [128][64] xT rows (16 KB)

    const int t = threadIdx.x;
    // XCD-aware decode: all 32 blocks of a (b,chunk) group share d%8.
    const int d = blockIdx.x;                // 0..1023
    const int xcd = d & 7;
    const int q = d >> 3;                    // 0..127
    const int w = q & 31;                    // within-group: mtile + ntile
    const int mtile = w & 7;
    const int ntile = w >> 3;                // 0..3
    const int gq = q >> 5;                   // 0..3
    const int g = gq * 8 + xcd;              // group id 0..31
    const int b = g & 7;
    const int kc = g >> 3;                   // K-chunk 0..3
    const int m0 = mtile * 64;
    const int cb0 = ntile * 128;             // output col base
    const int nc0 = kc * 1024;               // K-chunk base

    const int l = t & 63, wid = t >> 6;
    const int wm = wid >> 2, wn = wid & 3;

    f32x4 acc[2][2];
#pragma unroll
    for (int i = 0; i < 2; ++i)
#pragma unroll
        for (int j = 0; j < 2; ++j) acc[i][j] = (f32x4){0.f, 0.f, 0.f, 0.f};

    // A-tile generation: thread owns (row=t>>3, LDS chunk=t&7) for global
    // n-chunk gch = sch ^ (row&7) (src-pre-swizzle).
    const int a_row = t >> 3, a_sch = t & 7;
    const int a_gch = a_sch ^ (a_row & 7);
    const float gm = gp[(size_t)b * M_ + m0 + a_row];
    const float sigma = __expf(log_sigma[0]);
    const float ninv2s2 = -0.5f / (sigma * sigma);
    const float* pb = pos + (size_t)b * N_ + nc0 + a_gch * 8;
    u16* a_wr = As + a_row * 64 + a_sch * 8;

    const u16* xb = xT + ((size_t)b * D_ + cb0) * N_ + nc0;

    const int fr = l & 15, fj = l >> 4;

    for (int ks = 0; ks < 16; ++ks) {
        const int kk = ks * 64;
        __syncthreads();                     // prev compute done
        // B stage: 128 rows x 64 k = 1024 chunks, 2/thread (async)
#pragma unroll
        for (int i = 0; i < 2; ++i) {
            const int cid = t + i * 512;
            const int brow = cid >> 3, bsch = cid & 7;
            gload16(xb + (size_t)brow * N_ + kk + ((bsch ^ (brow & 7)) * 8),
                    Bs + (size_t)wid * 512 + i * 4096);
        }
        // A compute: 8 RBF weights (hw cvt_pk), overlaps B flight
        {
            float4 p0 = *reinterpret_cast<const float4*>(pb + kk);
            float4 p1 = *reinterpret_cast<const float4*>(pb + kk + 4);
            float4 ea, eb;
            float d0 = gm - p0.x, d1 = gm - p0.y, d2 = gm - p0.z, d3 = gm - p0.w;
            float d4 = gm - p1.x, d5 = gm - p1.y, d6 = gm - p1.z, d7 = gm - p1.w;
            ea.x = __expf(d0 * d0 * ninv2s2); ea.y = __expf(d1 * d1 * ninv2s2);
            ea.z = __expf(d2 * d2 * ninv2s2); ea.w = __expf(d3 * d3 * ninv2s2);
            eb.x = __expf(d4 * d4 * ninv2s2); eb.y = __expf(d5 * d5 * ninv2s2);
            eb.z = __expf(d6 * d6 * ninv2s2); eb.w = __expf(d7 * d7 * ninv2s2);
            *reinterpret_cast<u16x8*>(a_wr) = pack8(ea, eb);
        }
        __syncthreads();                     // B landed + A ds_writes visible

#pragma unroll
        for (int kl = 0; kl < 2; ++kl) {
            const int cbase = kl * 4 + fj;
            const int ar0 = wm * 32 + fr, ar1 = ar0 + 16;
            bf16x8 a0 = *reinterpret_cast<const bf16x8*>(
                As + ar0 * 64 + ((cbase ^ (ar0 & 7)) * 8));
            bf16x8 a1 = *reinterpret_cast<const bf16x8*>(
                As + ar1 * 64 + ((cbase ^ (ar1 & 7)) * 8));
#pragma unroll
            for (int nf = 0; nf < 2; ++nf) {
                const int bcol = wn * 32 + nf * 16 + fr;
                bf16x8 bw = *reinterpret_cast<const bf16x8*>(
                    Bs + bcol * 64 + ((cbase ^ (bcol & 7)) * 8));
                acc[0][nf] = __builtin_amdgcn_mfma_f32_16x16x32_bf16(a0, bw, acc[0][nf], 0, 0, 0);
                acc[1][nf] = __builtin_amdgcn_mfma_f32_16x16x32_bf16(a1, bw, acc[1][nf], 0, 0, 0);
            }
        }
    }

    // plain coalesced stores of this K-chunk's partial (no RMW, no memset)
    float* pb_out = part + ((size_t)(kc * B_ + b) * M_) * D_;
#pragma unroll
    for (int mf = 0; mf < 2; ++mf)
#pragma unroll
        for (int nf = 0; nf < 2; ++nf) {
            const int col = cb0 + wn * 32 + nf * 16 + fr;
#pragma unroll
            for (int r = 0; r < 4; ++r) {
                const int m = m0 + wm * 32 + mf * 16 + fj * 4 + r;
                pb_out[(size_t)m * D_ + col] = acc[mf][nf][r];
            }
        }
}

// ---------------------------------------------------------------------------
// Partial reduction: field = part0 + part1 + part2 + part3. 32MB -> 8MB.
// ---------------------------------------------------------------------------
__global__ __launch_bounds__(256)
void k_sum(const float* __restrict__ part, float* __restrict__ field)
{
    const size_t i = ((size_t)blockIdx.x * 256 + threadIdx.x) * 4;
    const size_t S = (size_t)B_ * M_ * D_;
    float4 v0 = *reinterpret_cast<const float4*>(part + i);
    float4 v1 = *reinterpret_cast<const float4*>(part + S + i);
    float4 v2 = *reinterpret_cast<const float4*>(part + 2 * S + i);
    float4 v3 = *reinterpret_cast<const float4*>(part + 3 * S + i);
    float4 o;
    o.x = (v0.x + v1.x) + (v2.x + v3.x);
    o.y = (v0.y + v1.y) + (v2.y + v3.y);
    o.z = (v0.z + v1.z) + (v2.z + v3.z);
    o.w = (v0.w + v1.w) + (v2.w + v3.w);
    *reinterpret_cast<float4*>(field + i) = o;
}

// ---------------------------------------------------------------------------
// Diffusion step (round-14 known-good): fout = fin + dt*(alpha*lap + tanh(...)).
// WiT B-tiles staged per K-step via global_load_lds (BK=64, 8 steps,
// chunk^(row&7) src-pre-swizzle). fs (A) resident; Cs aliases Bs post-GEMM.
// grid (M/16, D/256, B), 256 thr, 49 KB dyn LDS -> 2 blocks/CU.
// ---------------------------------------------------------------------------
__global__ __launch_bounds__(256, 8)
void k_diffuse(const float* __restrict__ fin, const u16* __restrict__ WiT,
               const float* __restrict__ bi, const float* __restrict__ alpha_p,
               float* __restrict__ fout)
{
    extern __shared__ u16 dsm[];     // 49408 B
    u16* fs = dsm;                   // [16][520] bf16 field rows (16.6 KB)
    u16* Bs = dsm + 16 * 520;        // [256][64] WiT tile (32 KB)
    float* Cs = (float*)Bs;          // [16][260] fp32, aliases Bs post-GEMM

    const int t = threadIdx.x;
    const int m0 = blockIdx.x * 16;
    const int cb0 = blockIdx.y * 256;
    const int b = blockIdx.z;
    const int l = t & 63, wn = t >> 6;
    const int fr = l & 15, fj = l >> 4;
    const float* fb = fin + (size_t)b * M_ * D_;

    {   // stage fs: 16 rows x 512 cols fp32 -> bf16 (hw cvt)
        const int row = t >> 4, ch = (t & 15) * 32;
        const float* src = fb + (size_t)(m0 + row) * D_ + ch;
#pragma unroll
        for (int j = 0; j < 4; ++j) {
            float4 v0 = *reinterpret_cast<const float4*>(src + j * 8);
            float4 v1 = *reinterpret_cast<const float4*>(src + j * 8 + 4);
            *reinterpret_cast<u16x8*>(fs + row * 520 + ch + j * 8) = pack8(v0, v1);
        }
    }

    f32x4 acc[4];
#pragma unroll
    for (int i = 0; i < 4; ++i) acc[i] = (f32x4){0.f, 0.f, 0.f, 0.f};

    const u16* wb = WiT + (size_t)cb0 * D_;

    for (int ks = 0; ks < 8; ++ks) {
        const int kk = ks * 64;
        __syncthreads();                 // iter0: fs writes flushed; else: prev Bs reads done
        // stage B: 256 rows (Wi output-cols) x 64 k, 2048 chunks, 8/thread
#pragma unroll
        for (int i = 0; i < 8; ++i) {
            const int cid = t + i * 256;
            const int brow = cid >> 3, bsch = cid & 7;
            gload16(wb + (size_t)brow * D_ + kk + ((bsch ^ (brow & 7)) * 8),
                    Bs + (i * 256 + wn * 64) * 8);
        }
        __syncthreads();                 // loads landed

#pragma unroll
        for (int kl = 0; kl < 2; ++kl) {
            const int cbase = kl * 4 + fj;
            bf16x8 a = *reinterpret_cast<const bf16x8*>(
                fs + fr * 520 + kk + kl * 32 + fj * 8);
#pragma unroll
            for (int nf = 0; nf < 4; ++nf) {
                const int bcol = wn * 64 + nf * 16 + fr;
                bf16x8 bw = *reinterpret_cast<const bf16x8*>(
                    Bs + bcol * 64 + ((cbase ^ (bcol & 7)) * 8));
                acc[nf] = __builtin_amdgcn_mfma_f32_16x16x32_bf16(a, bw, acc[nf], 0, 0, 0);
            }
        }
    }

    __syncthreads();   // all Bs reads done before Cs (alias) overwrite
    // stage gemm+bias into Cs (scatter, conflict-free by 260 stride)
#pragma unroll
    for (int nf = 0; nf < 4; ++nf) {
        const int cl = wn * 64 + nf * 16 + fr;
        const float bic = bi[cb0 + cl];
#pragma unroll
        for (int r = 0; r < 4; ++r)
            Cs[(fj * 4 + r) * 260 + cl] = acc[nf][r] + bic;
    }
    __syncthreads();

    // row pass: wave wn owns rows wn*4..+3, fully vectorized
    const float al = alpha_p[0];
    float* fob = fout + (size_t)b * M_ * D_;
#pragma unroll
    for (int i = 0; i < 4; ++i) {
        const int row = wn * 4 + i;
        const int m = m0 + row;
        const int mu_ = m > 0 ? m - 1 : 0;
        const int md = m < M_ - 1 ? m + 1 : M_ - 1;
        const int cl = cb0 + l * 4;
        float4 g  = *reinterpret_cast<const float4*>(&Cs[row * 260 + l * 4]);
        float4 fc = *reinterpret_cast<const float4*>(fb + (size_t)m * D_ + cl);
        float4 fu = *reinterpret_cast<const float4*>(fb + (size_t)mu_ * D_ + cl);
        float4 fd = *reinterpret_cast<const float4*>(fb + (size_t)md * D_ + cl);
        float4 o;
        o.x = fc.x + DT_ * (al * (fu.x + fd.x - 2.f * fc.x) + tanhf(g.x));
        o.y = fc.y + DT_ * (al * (fu.y + fd.y - 2.f * fc.y) + tanhf(g.y));
        o.z = fc.z + DT_ * (al * (fu.z + fd.z - 2.f * fc.z) + tanhf(g.z));
        o.w = fc.w + DT_ * (al * (fu.w + fd.w - 2.f * fc.w) + tanhf(g.w));
        *reinterpret_cast<float4*>(fob + (size_t)m * D_ + cl) = o;
    }
}

// ---------------------------------------------------------------------------
// Tail part 1: enh = LN1(lerp(field) + x) -> bf16.
// ---------------------------------------------------------------------------
__global__ __launch_bounds__(256)
void k_enh(const float* __restrict__ x, const float* __restrict__ pos,
           const float* __restrict__ field, const float* __restrict__ g1,
           const float* __restrict__ b1, u16* __restrict__ enh)
{
    const int t = threadIdx.x;
    const int wid = t >> 6, l = t & 63;
    const int n = blockIdx.x * 4 + wid;
    const int b = blockIdx.y;
    const int c = l * 8;

    const float* xr = x + ((size_t)b * N_ + n) * D_ + c;
    float4 xa = *reinterpret_cast<const float4*>(xr);
    float4 xb = *reinterpret_cast<const float4*>(xr + 4);
    const float p = pos[(size_t)b * N_ + n];
    float u = p * (float)(M_ - 1);
    int i0 = (int)floorf(u);
    i0 = i0 < 0 ? 0 : (i0 > M_ - 2 ? M_ - 2 : i0);
    const float w = u - (float)i0;
    const float* fp0 = field + ((size_t)b * M_ + i0) * D_ + c;
    float4 f0a = *reinterpret_cast<const float4*>(fp0);
    float4 f0b = *reinterpret_cast<const float4*>(fp0 + 4);
    float4 f1a = *reinterpret_cast<const float4*>(fp0 + D_);
    float4 f1b = *reinterpret_cast<const float4*>(fp0 + D_ + 4);

    float s[8];
    s[0] = f0a.x + w * (f1a.x - f0a.x) + xa.x;
    s[1] = f0a.y + w * (f1a.y - f0a.y) + xa.y;
    s[2] = f0a.z + w * (f1a.z - f0a.z) + xa.z;
    s[3] = f0a.w + w * (f1a.w - f0a.w) + xa.w;
    s[4] = f0b.x + w * (f1b.x - f0b.x) + xb.x;
    s[5] = f0b.y + w * (f1b.y - f0b.y) + xb.y;
    s[6] = f0b.z + w * (f1b.z - f0b.z) + xb.z;
    s[7] = f0b.w + w * (f1b.w - f0b.w) + xb.w;

    float sum = 0.f, ss = 0.f;
#pragma unroll
    for (int j = 0; j < 8; ++j) { sum += s[j]; ss += s[j] * s[j]; }
#pragma unroll
    for (int off = 1; off <= 32; off <<= 1) {
        sum += __shfl_xor(sum, off);
        ss  += __shfl_xor(ss, off);
    }
    const float mu = sum * (1.f / 512.f);
    const float rs = rsqrtf(ss * (1.f / 512.f) - mu * mu + EPS_);

    float4 ga = *reinterpret_cast<const float4*>(g1 + c);
    float4 gb = *reinterpret_cast<const float4*>(g1 + c + 4);
    float4 ba = *reinterpret_cast<const float4*>(b1 + c);
    float4 bb = *reinterpret_cast<const float4*>(b1 + c + 4);
    float4 ea, eb;
    ea.x = (s[0] - mu) * rs * ga.x + ba.x;
    ea.y = (s[1] - mu) * rs * ga.y + ba.y;
    ea.z = (s[2] - mu) * rs * ga.z + ba.z;
    ea.w = (s[3] - mu) * rs * ga.w + ba.w;
    eb.x = (s[4] - mu) * rs * gb.x + bb.x;
    eb.y = (s[5] - mu) * rs * gb.y + bb.y;
    eb.z = (s[6] - mu) * rs * gb.z + bb.z;
    eb.w = (s[7] - mu) * rs * gb.w + bb.w;
    *reinterpret_cast<u16x8*>(enh + ((size_t)b * N_ + n) * D_ + c) = pack8(ea, eb);
}

// ---------------------------------------------------------------------------
// Tail part 2: out = LN2(enh @ WoT + bo + enh).
// Single-buffer BK=64, 72KB dyn LDS, Cs[32][516] 2-pass epilogue.
// NEW: residual fragments preloaded to registers before the K-loop
// (removes the 16MB late HBM re-fetch + epilogue load latency).
// ---------------------------------------------------------------------------
__global__ __launch_bounds__(512, 4)
void k_gemm_ln(const u16* __restrict__ enh, const u16* __restrict__ WoT,
               const float* __restrict__ bo, const float* __restrict__ g2,
               const float* __restrict__ b2, float* __restrict__ out)
{
    extern __shared__ u16 smem[];            // 72 KB
    u16* As = smem;                          // [64][64] linear+src-swz (8 KB)
    u16* Bs = smem + 64 * 64;                // [512][64] linear+src-swz (64 KB)
    float* Cs = (float*)smem;                // [32][516] fp32, reused post-GEMM

    const int t = threadIdx.x;
    const int r0 = blockIdx.x * 64;          // row in flattened [B*N][D]
    const int l = t & 63, wid = t >> 6;
    const int wm = wid >> 2, wn = wid & 3;

    f32x4 acc[2][8];
#pragma unroll
    for (int i = 0; i < 2; ++i)
#pragma unroll
        for (int j = 0; j < 8; ++j) acc[i][j] = (f32x4){0.f, 0.f, 0.f, 0.f};

    // preload residual fragments (epilogue rows/cols) into registers
    u16x4 res[2][4][2];
#pragma unroll
    for (int mf = 0; mf < 2; ++mf)
#pragma unroll
        for (int i = 0; i < 4; ++i) {
            const int lr = wid * 4 + i;
            const int grow = r0 + (lr >> 4) * 32 + mf * 16 + (lr & 15);
            res[mf][i][0] = *reinterpret_cast<const u16x4*>(enh + (size_t)grow * D_ + l * 4);
            res[mf][i][1] = *reinterpret_cast<const u16x4*>(enh + (size_t)grow * D_ + 256 + l * 4);
        }

    // staging assignments (chunk = 8 bf16 = 16B)
    const int a_row = t >> 3, a_sch = t & 7;                  // A: 512 chunks
    const u16* a_src = enh + (size_t)(r0 + a_row) * D_ + (a_sch ^ (a_row & 7)) * 8;
    u16* a_dst = As + (size_t)wid * 512;                      // wave-uniform base

    const int fr = l & 15, fj = l >> 4;                       // frag coords

    for (int ks = 0; ks < 8; ++ks) {
        const int kk = ks * 64;
        __syncthreads();                     // prev compute done (tiles reusable)
        gload16(a_src + kk, a_dst);
#pragma unroll
        for (int i = 0; i < 8; ++i) {
            const int cid = t + i * 512;                      // B chunk id
            const int brow = cid >> 3, bsch = cid & 7;
            gload16(WoT + (size_t)brow * D_ + kk + ((bsch ^ (brow & 7)) * 8),
                    Bs + (size_t)wid * 512 + i * 4096);
        }
        __syncthreads();                     // loads landed (vmcnt0 at barrier)

#pragma unroll
        for (int kl = 0; kl < 2; ++kl) {     // two k-halves of 32
            const int cbase = kl * 4 + fj;   // chunk index 0..7
            const int ar0 = wm * 32 + fr, ar1 = ar0 + 16;
            bf16x8 a0 = *reinterpret_cast<const bf16x8*>(
                As + ar0 * 64 + ((cbase ^ (ar0 & 7)) * 8));
            bf16x8 a1 = *reinterpret_cast<const bf16x8*>(
                As + ar1 * 64 + ((cbase ^ (ar1 & 7)) * 8));
#pragma unroll
            for (int nf = 0; nf < 8; ++nf) {
                const int bcol = wn * 128 + nf * 16 + fr;
                bf16x8 bw = *reinterpret_cast<const bf16x8*>(
                    Bs + bcol * 64 + ((cbase ^ (bcol & 7)) * 8));
                acc[0][nf] = __builtin_amdgcn_mfma_f32_16x16x32_bf16(a0, bw, acc[0][nf], 0, 0, 0);
                acc[1][nf] = __builtin_amdgcn_mfma_f32_16x16x32_bf16(a1, bw, acc[1][nf], 0, 0, 0);
            }
        }
    }

#pragma unroll
    for (int mf = 0; mf < 2; ++mf) {
        __syncthreads();   // pass separation (protects Cs reuse vs B reads / prev pass)
        // scatter acc + bias into Cs; localrow = wm*16 + (l>>4)*4 + r
#pragma unroll
        for (int nf = 0; nf < 8; ++nf) {
            const int col = wn * 128 + nf * 16 + fr;
            const float boc = bo[col];
#pragma unroll
            for (int r = 0; r < 4; ++r)
                Cs[(wm * 16 + fj * 4 + r) * 516 + col] = acc[mf][nf][r] + boc;
        }
        __syncthreads();
        // row pass: wave wid owns localrows wid*4..+3; cols {l*4, 256+l*4}
#pragma unroll
        for (int i = 0; i < 4; ++i) {
            const int lr = wid * 4 + i;
            const int grow = r0 + (lr >> 4) * 32 + mf * 16 + (lr & 15);
            const int c1 = l * 4, c2 = 256 + l * 4;
            float4 fa = *reinterpret_cast<const float4*>(&Cs[lr * 516 + c1]);
            float4 fb4 = *reinterpret_cast<const float4*>(&Cs[lr * 516 + c2]);
            const u16x4 e1 = res[mf][i][0];
            const u16x4 e2 = res[mf][i][1];
            float v[8];
            v[0] = fa.x + bf2f(e1[0]); v[1] = fa.y + bf2f(e1[1]);
            v[2] = fa.z + bf2f(e1[2]); v[3] = fa.w + bf2f(e1[3]);
            v[4] = fb4.x + bf2f(e2[0]); v[5] = fb4.y + bf2f(e2[1]);
            v[6] = fb4.z + bf2f(e2[2]); v[7] = fb4.w + bf2f(e2[3]);

            float sum = 0.f, ss = 0.f;
#pragma unroll
            for (int j = 0; j < 8; ++j) { sum += v[j]; ss += v[j] * v[j]; }
#pragma unroll
            for (int off = 1; off <= 32; off <<= 1) {
                sum += __shfl_xor(sum, off);
                ss  += __shfl_xor(ss, off);
            }
            const float mu = sum * (1.f / 512.f);
            const float rs = rsqrtf(ss * (1.f / 512.f) - mu * mu + EPS_);

            float4 ga = *reinterpret_cast<const float4*>(g2 + c1);
            float4 gb = *reinterpret_cast<const float4*>(g2 + c2);
            float4 ba = *reinterpret_cast<const float4*>(b2 + c1);
            float4 bb = *reinterpret_cast<const float4*>(b2 + c2);
            float4 oa, ob;
            oa.x = (v[0] - mu) * rs * ga.x + ba.x;
            oa.y = (v[1] - mu) * rs * ga.y + ba.y;
            oa.z = (v[2] - mu) * rs * ga.z + ba.z;
            oa.w = (v[3] - mu) * rs * ga.w + ba.w;
            ob.x = (v[4] - mu) * rs * gb.x + bb.x;
            ob.y = (v[5] - mu) * rs * gb.y + bb.y;
            ob.z = (v[6] - mu) * rs * gb.z + bb.z;
            ob.w = (v[7] - mu) * rs * gb.w + bb.w;
            float* orow = out + (size_t)grow * D_;
            *reinterpret_cast<float4*>(orow + c1) = oa;
            *reinterpret_cast<float4*>(orow + c2) = ob;
        }
    }
}

extern "C" void kernel_launch(void* const* d_in, const int* in_sizes, int n_in,
                              void* d_out, int out_size, void* d_ws, size_t ws_size,
                              hipStream_t stream) {
    (void)in_sizes; (void)n_in; (void)out_size; (void)ws_size;
    const float* x   = (const float*)d_in[0];
    const float* pos = (const float*)d_in[1];
    const float* gp  = (const float*)d_in[2];
    const float* ls  = (const float*)d_in[3];
    const float* al  = (const float*)d_in[4];
    const float* Wi  = (const float*)d_in[5];
    const float* bi  = (const float*)d_in[6];
    const float* g1  = (const float*)d_in[7];
    const float* b1  = (const float*)d_in[8];
    const float* Wo  = (const float*)d_in[9];
    const float* bo  = (const float*)d_in[10];
    const float* g2  = (const float*)d_in[11];
    const float* b2  = (const float*)d_in[12];
    float* out = (float*)d_out;

    float* f0 = (float*)d_ws;                              // 8 MB fp32 field
    float* f1 = f0 + (size_t)B_ * M_ * D_;                 // 8 MB ping-pong
    u16* xT  = (u16*)(f1 + (size_t)B_ * M_ * D_);          // 32 MB bf16 x^T
    u16* WiT = xT + (size_t)B_ * D_ * N_;                  // 512 KB
    u16* WoT = WiT + (size_t)D_ * D_;                      // 512 KB
    u16* enh = xT;                                         // alias: xT dead after project
    float* part = (float*)d_out;                           // 32 MB partials in d_out
                                                           // (dead before k_gemm_ln writes)

    const int smGemm = 64 * 64 * 2 + 512 * 64 * 2;         // 73728 B (k_gemm_ln)
    const int smProj = 64 * 64 * 2 + 128 * 64 * 2;         // 24576 B (k_projgemm)
    const int smDiff = 16 * 520 * 2 + 256 * 64 * 2;        // 49408 B (k_diffuse)
    hipFuncSetAttribute(reinterpret_cast<const void*>(k_gemm_ln),
                        hipFuncAttributeMaxDynamicSharedMemorySize, smGemm);
    hipFuncSetAttribute(reinterpret_cast<const void*>(k_projgemm),
                        hipFuncAttributeMaxDynamicSharedMemorySize, smProj);
    hipFuncSetAttribute(reinterpret_cast<const void*>(k_diffuse),
                        hipFuncAttributeMaxDynamicSharedMemorySize, smDiff);

    k_prep_T<<<dim3(D_ / 64, N_ / 64, B_), 256, 0, stream>>>(x, xT, N_, D_);
    k_prep_T<<<dim3(D_ / 64, D_ / 64, 1), 256, 0, stream>>>(Wi, WiT, D_, D_);
    k_prep_T<<<dim3(D_ / 64, D_ / 64, 1), 256, 0, stream>>>(Wo, WoT, D_, D_);
    k_projgemm<<<dim3(1024), 512, smProj, stream>>>(pos, gp, ls, xT, part);
    k_sum<<<dim3((B_ * M_ * D_) / (256 * 4)), 256, 0, stream>>>(part, f0);
    k_diffuse<<<dim3(M_ / 16, D_ / 256, B_), 256, smDiff, stream>>>(f0, WiT, bi, al, f1);
    k_diffuse<<<dim3(M_ / 16, D_ / 256, B_), 256, smDiff, stream>>>(f1, WiT, bi, al, f0);
    k_diffuse<<<dim3(M_ / 16, D_ / 256, B_), 256, smDiff, stream>>>(f0, WiT, bi, al, f1);
    k_diffuse<<<dim3(M_ / 16, D_ / 256, B_), 256, smDiff, stream>>>(f1, WiT, bi, al, f0);
    k_enh<<<dim3(N_ / 4, B_), 256, 0, stream>>>(x, pos, f0, g1, b1, enh);
    k_gemm_ln<<<dim3(B_ * N_ / 64), 512, smGemm, stream>>>(enh, WoT, bo, g2, b2, out);
}

// Round 18
// 165.404 us; speedup vs baseline: 1.0506x; 1.0365x over previous
//
#include <hip/hip_runtime.h>
#include <cmath>

#define B_ 8
#define N_ 4096
#define D_ 512
#define M_ 512
#define EPS_ 1e-5f
#define DT_ 0.25f

typedef unsigned short u16;
typedef unsigned int u32;
typedef __attribute__((ext_vector_type(8))) u16 u16x8;
typedef __attribute__((ext_vector_type(4))) u16 u16x4;
typedef __attribute__((ext_vector_type(8))) short bf16x8;
typedef __attribute__((ext_vector_type(4))) float f32x4;

__device__ __forceinline__ float bf2f(u16 h) {
    return __builtin_bit_cast(float, (u32)h << 16);
}
// hardware packed fp32->bf16 (gfx950 v_cvt_pk_bf16_f32, RNE) [T12 recipe]
__device__ __forceinline__ u32 cvtpk(float lo, float hi) {
    u32 r;
    asm("v_cvt_pk_bf16_f32 %0, %1, %2" : "=v"(r) : "v"(lo), "v"(hi));
    return r;
}
__device__ __forceinline__ u16 f2bf(float f) { return (u16)cvtpk(f, 0.f); }
__device__ __forceinline__ u16x8 pack8(float4 a, float4 b) {
    union { u32 w[4]; u16x8 o; } u;
    u.w[0] = cvtpk(a.x, a.y); u.w[1] = cvtpk(a.z, a.w);
    u.w[2] = cvtpk(b.x, b.y); u.w[3] = cvtpk(b.z, b.w);
    return u.o;
}

// async global->LDS, 16B per lane; lds must be wave-uniform base (+lane*16 HW)
__device__ __forceinline__ void gload16(const void* g, void* l) {
    __builtin_amdgcn_global_load_lds(
        (const __attribute__((address_space(1))) void*)g,
        (__attribute__((address_space(3))) void*)l, 16, 0, 0);
}

// ---------------------------------------------------------------------------
// Transpose + fp32->bf16: src [Z][R][C] -> dst [Z][C][R]
// ---------------------------------------------------------------------------
__global__ __launch_bounds__(256)
void k_prep_T(const float* __restrict__ src, u16* __restrict__ dst, int R, int C)
{
    __shared__ float tile[64][65];
    const int t = threadIdx.x;
    const int c0 = blockIdx.x * 64;
    const int r0 = blockIdx.y * 64;
    const int z  = blockIdx.z;
    const float* s = src + (size_t)z * R * C;
    u16* d = dst + (size_t)z * R * C;
    const int rl = t >> 4, cc = (t & 15) * 4;
#pragma unroll
    for (int i = 0; i < 4; ++i) {
        float4 v = *reinterpret_cast<const float4*>(s + (size_t)(r0 + rl + i * 16) * C + c0 + cc);
        tile[rl + i * 16][cc + 0] = v.x;
        tile[rl + i * 16][cc + 1] = v.y;
        tile[rl + i * 16][cc + 2] = v.z;
        tile[rl + i * 16][cc + 3] = v.w;
    }
    __syncthreads();
#pragma unroll
    for (int i = 0; i < 2; ++i) {
        int q = t + i * 256;
        int cl = q >> 3, rc = (q & 7) * 8;
        float4 va, vb;
        va.x = tile[rc + 0][cl]; va.y = tile[rc + 1][cl];
        va.z = tile[rc + 2][cl]; va.w = tile[rc + 3][cl];
        vb.x = tile[rc + 4][cl]; vb.y = tile[rc + 5][cl];
        vb.z = tile[rc + 6][cl]; vb.w = tile[rc + 7][cl];
        *reinterpret_cast<u16x8*>(d + (size_t)(c0 + cl) * R + r0 + rc) = pack8(va, vb);
    }
}

// ---------------------------------------------------------------------------
// Projection GEMM, fused RBF A-tile (hw cvt_pk), tile 64x128, 24KB LDS,
// 4 blocks/CU, grid 1024 XCD-grouped. NO ATOMICS: each K-chunk writes its
// partial to part[kc][b][m][d] in BF16 (plain coalesced stores); k_sum reduces.
// ---------------------------------------------------------------------------
__global__ __launch_bounds__(512, 4)
void k_projgemm(const float* __restrict__ pos, const float* __restrict__ gp,
                const float* __restrict__ log_sigma, const u16* __restrict__ xT,
                u16* __restrict__ part)
{
    extern __shared__ u16 smem[];            // 24 KB
    u16* As = smem;                          // [64][64] kern tile (8 KB)
    u16* Bs = smem + 64 * 64;                // [128][64] xT rows (16 KB)

    const int t = threadIdx.x;
    // XCD-aware decode: all 32 blocks of a (b,chunk) group share d%8.
    const int d = blockIdx.x;                // 0..1023
    const int xcd = d & 7;
    const int q = d >> 3;                    // 0..127
    const int w = q & 31;                    // within-group: mtile + ntile
    const int mtile = w & 7;
    const int ntile = w >> 3;                // 0..3
    const int gq = q >> 5;                   // 0..3
    const int g = gq * 8 + xcd;              // group id 0..31
    const int b = g & 7;
    const int kc = g >> 3;                   // K-chunk 0..3
    const int m0 = mtile * 64;
    const int cb0 = ntile * 128;             // output col base
    const int nc0 = kc * 1024;               // K-chunk base

    const int l = t & 63, wid = t >> 6;
    const int wm = wid >> 2, wn = wid & 3;

    f32x4 acc[2][2];
#pragma unroll
    for (int i = 0; i < 2; ++i)
#pragma unroll
        for (int j = 0; j < 2; ++j) acc[i][j] = (f32x4){0.f, 0.f, 0.f, 0.f};

    // A-tile generation: thread owns (row=t>>3, LDS chunk=t&7) for global
    // n-chunk gch = sch ^ (row&7) (src-pre-swizzle).
    const int a_row = t >> 3, a_sch = t & 7;
    const int a_gch = a_sch ^ (a_row & 7);
    const float gm = gp[(size_t)b * M_ + m0 + a_row];
    const float sigma = __expf(log_sigma[0]);
    const float ninv2s2 = -0.5f / (sigma * sigma);
    const float* pb = pos + (size_t)b * N_ + nc0 + a_gch * 8;
    u16* a_wr = As + a_row * 64 + a_sch * 8;

    const u16* xb = xT + ((size_t)b * D_ + cb0) * N_ + nc0;

    const int fr = l & 15, fj = l >> 4;

    for (int ks = 0; ks < 16; ++ks) {
        const int kk = ks * 64;
        __syncthreads();                     // prev compute done
        // B stage: 128 rows x 64 k = 1024 chunks, 2/thread (async)
#pragma unroll
        for (int i = 0; i < 2; ++i) {
            const int cid = t + i * 512;
            const int brow = cid >> 3, bsch = cid & 7;
            gload16(xb + (size_t)brow * N_ + kk + ((bsch ^ (brow & 7)) * 8),
                    Bs + (size_t)wid * 512 + i * 4096);
        }
        // A compute: 8 RBF weights (hw cvt_pk), overlaps B flight
        {
            float4 p0 = *reinterpret_cast<const float4*>(pb + kk);
            float4 p1 = *reinterpret_cast<const float4*>(pb + kk + 4);
            float4 ea, eb;
            float d0 = gm - p0.x, d1 = gm - p0.y, d2 = gm - p0.z, d3 = gm - p0.w;
            float d4 = gm - p1.x, d5 = gm - p1.y, d6 = gm - p1.z, d7 = gm - p1.w;
            ea.x = __expf(d0 * d0 * ninv2s2); ea.y = __expf(d1 * d1 * ninv2s2);
            ea.z = __expf(d2 * d2 * ninv2s2); ea.w = __expf(d3 * d3 * ninv2s2);
            eb.x = __expf(d4 * d4 * ninv2s2); eb.y = __expf(d5 * d5 * ninv2s2);
            eb.z = __expf(d6 * d6 * ninv2s2); eb.w = __expf(d7 * d7 * ninv2s2);
            *reinterpret_cast<u16x8*>(a_wr) = pack8(ea, eb);
        }
        __syncthreads();                     // B landed + A ds_writes visible

#pragma unroll
        for (int kl = 0; kl < 2; ++kl) {
            const int cbase = kl * 4 + fj;
            const int ar0 = wm * 32 + fr, ar1 = ar0 + 16;
            bf16x8 a0 = *reinterpret_cast<const bf16x8*>(
                As + ar0 * 64 + ((cbase ^ (ar0 & 7)) * 8));
            bf16x8 a1 = *reinterpret_cast<const bf16x8*>(
                As + ar1 * 64 + ((cbase ^ (ar1 & 7)) * 8));
#pragma unroll
            for (int nf = 0; nf < 2; ++nf) {
                const int bcol = wn * 32 + nf * 16 + fr;
                bf16x8 bw = *reinterpret_cast<const bf16x8*>(
                    Bs + bcol * 64 + ((cbase ^ (bcol & 7)) * 8));
                acc[0][nf] = __builtin_amdgcn_mfma_f32_16x16x32_bf16(a0, bw, acc[0][nf], 0, 0, 0);
                acc[1][nf] = __builtin_amdgcn_mfma_f32_16x16x32_bf16(a1, bw, acc[1][nf], 0, 0, 0);
            }
        }
    }

    // plain coalesced bf16 stores of this K-chunk's partial (no RMW)
    u16* pb_out = part + ((size_t)(kc * B_ + b) * M_) * D_;
#pragma unroll
    for (int mf = 0; mf < 2; ++mf)
#pragma unroll
        for (int nf = 0; nf < 2; ++nf) {
            const int col = cb0 + wn * 32 + nf * 16 + fr;
#pragma unroll
            for (int r = 0; r < 4; ++r) {
                const int m = m0 + wm * 32 + mf * 16 + fj * 4 + r;
                pb_out[(size_t)m * D_ + col] = f2bf(acc[mf][nf][r]);
            }
        }
}

// ---------------------------------------------------------------------------
// Partial reduction: field = sum of 4 bf16 partials. 16MB read -> 8MB write.
// grid 1024 x 256 thr, 8 elements/thread.
// ---------------------------------------------------------------------------
__global__ __launch_bounds__(256)
void k_sum(const u16* __restrict__ part, float* __restrict__ field)
{
    const size_t i = ((size_t)blockIdx.x * 256 + threadIdx.x) * 8;
    const size_t S = (size_t)B_ * M_ * D_;
    u16x8 v0 = *reinterpret_cast<const u16x8*>(part + i);
    u16x8 v1 = *reinterpret_cast<const u16x8*>(part + S + i);
    u16x8 v2 = *reinterpret_cast<const u16x8*>(part + 2 * S + i);
    u16x8 v3 = *reinterpret_cast<const u16x8*>(part + 3 * S + i);
    float4 o1, o2;
    o1.x = (bf2f(v0[0]) + bf2f(v1[0])) + (bf2f(v2[0]) + bf2f(v3[0]));
    o1.y = (bf2f(v0[1]) + bf2f(v1[1])) + (bf2f(v2[1]) + bf2f(v3[1]));
    o1.z = (bf2f(v0[2]) + bf2f(v1[2])) + (bf2f(v2[2]) + bf2f(v3[2]));
    o1.w = (bf2f(v0[3]) + bf2f(v1[3])) + (bf2f(v2[3]) + bf2f(v3[3]));
    o2.x = (bf2f(v0[4]) + bf2f(v1[4])) + (bf2f(v2[4]) + bf2f(v3[4]));
    o2.y = (bf2f(v0[5]) + bf2f(v1[5])) + (bf2f(v2[5]) + bf2f(v3[5]));
    o2.z = (bf2f(v0[6]) + bf2f(v1[6])) + (bf2f(v2[6]) + bf2f(v3[6]));
    o2.w = (bf2f(v0[7]) + bf2f(v1[7])) + (bf2f(v2[7]) + bf2f(v3[7]));
    *reinterpret_cast<float4*>(field + i)     = o1;
    *reinterpret_cast<float4*>(field + i + 4) = o2;
}

// ---------------------------------------------------------------------------
// Diffusion step (round-14 known-good): fout = fin + dt*(alpha*lap + tanh(...)).
// WiT B-tiles staged per K-step via global_load_lds (BK=64, 8 steps,
// chunk^(row&7) src-pre-swizzle). fs (A) resident; Cs aliases Bs post-GEMM.
// grid (M/16, D/256, B), 256 thr, 49 KB dyn LDS -> 2 blocks/CU.
// ---------------------------------------------------------------------------
__global__ __launch_bounds__(256, 8)
void k_diffuse(const float* __restrict__ fin, const u16* __restrict__ WiT,
               const float* __restrict__ bi, const float* __restrict__ alpha_p,
               float* __restrict__ fout)
{
    extern __shared__ u16 dsm[];     // 49408 B
    u16* fs = dsm;                   // [16][520] bf16 field rows (16.6 KB)
    u16* Bs = dsm + 16 * 520;        // [256][64] WiT tile (32 KB)
    float* Cs = (float*)Bs;          // [16][260] fp32, aliases Bs post-GEMM

    const int t = threadIdx.x;
    const int m0 = blockIdx.x * 16;
    const int cb0 = blockIdx.y * 256;
    const int b = blockIdx.z;
    const int l = t & 63, wn = t >> 6;
    const int fr = l & 15, fj = l >> 4;
    const float* fb = fin + (size_t)b * M_ * D_;

    {   // stage fs: 16 rows x 512 cols fp32 -> bf16 (hw cvt)
        const int row = t >> 4, ch = (t & 15) * 32;
        const float* src = fb + (size_t)(m0 + row) * D_ + ch;
#pragma unroll
        for (int j = 0; j < 4; ++j) {
            float4 v0 = *reinterpret_cast<const float4*>(src + j * 8);
            float4 v1 = *reinterpret_cast<const float4*>(src + j * 8 + 4);
            *reinterpret_cast<u16x8*>(fs + row * 520 + ch + j * 8) = pack8(v0, v1);
        }
    }

    f32x4 acc[4];
#pragma unroll
    for (int i = 0; i < 4; ++i) acc[i] = (f32x4){0.f, 0.f, 0.f, 0.f};

    const u16* wb = WiT + (size_t)cb0 * D_;

    for (int ks = 0; ks < 8; ++ks) {
        const int kk = ks * 64;
        __syncthreads();                 // iter0: fs writes flushed; else: prev Bs reads done
        // stage B: 256 rows (Wi output-cols) x 64 k, 2048 chunks, 8/thread
#pragma unroll
        for (int i = 0; i < 8; ++i) {
            const int cid = t + i * 256;
            const int brow = cid >> 3, bsch = cid & 7;
            gload16(wb + (size_t)brow * D_ + kk + ((bsch ^ (brow & 7)) * 8),
                    Bs + (i * 256 + wn * 64) * 8);
        }
        __syncthreads();                 // loads landed

#pragma unroll
        for (int kl = 0; kl < 2; ++kl) {
            const int cbase = kl * 4 + fj;
            bf16x8 a = *reinterpret_cast<const bf16x8*>(
                fs + fr * 520 + kk + kl * 32 + fj * 8);
#pragma unroll
            for (int nf = 0; nf < 4; ++nf) {
                const int bcol = wn * 64 + nf * 16 + fr;
                bf16x8 bw = *reinterpret_cast<const bf16x8*>(
                    Bs + bcol * 64 + ((cbase ^ (bcol & 7)) * 8));
                acc[nf] = __builtin_amdgcn_mfma_f32_16x16x32_bf16(a, bw, acc[nf], 0, 0, 0);
            }
        }
    }

    __syncthreads();   // all Bs reads done before Cs (alias) overwrite
    // stage gemm+bias into Cs (scatter, conflict-free by 260 stride)
#pragma unroll
    for (int nf = 0; nf < 4; ++nf) {
        const int cl = wn * 64 + nf * 16 + fr;
        const float bic = bi[cb0 + cl];
#pragma unroll
        for (int r = 0; r < 4; ++r)
            Cs[(fj * 4 + r) * 260 + cl] = acc[nf][r] + bic;
    }
    __syncthreads();

    // row pass: wave wn owns rows wn*4..+3, fully vectorized
    const float al = alpha_p[0];
    float* fob = fout + (size_t)b * M_ * D_;
#pragma unroll
    for (int i = 0; i < 4; ++i) {
        const int row = wn * 4 + i;
        const int m = m0 + row;
        const int mu_ = m > 0 ? m - 1 : 0;
        const int md = m < M_ - 1 ? m + 1 : M_ - 1;
        const int cl = cb0 + l * 4;
        float4 g  = *reinterpret_cast<const float4*>(&Cs[row * 260 + l * 4]);
        float4 fc = *reinterpret_cast<const float4*>(fb + (size_t)m * D_ + cl);
        float4 fu = *reinterpret_cast<const float4*>(fb + (size_t)mu_ * D_ + cl);
        float4 fd = *reinterpret_cast<const float4*>(fb + (size_t)md * D_ + cl);
        float4 o;
        o.x = fc.x + DT_ * (al * (fu.x + fd.x - 2.f * fc.x) + tanhf(g.x));
        o.y = fc.y + DT_ * (al * (fu.y + fd.y - 2.f * fc.y) + tanhf(g.y));
        o.z = fc.z + DT_ * (al * (fu.z + fd.z - 2.f * fc.z) + tanhf(g.z));
        o.w = fc.w + DT_ * (al * (fu.w + fd.w - 2.f * fc.w) + tanhf(g.w));
        *reinterpret_cast<float4*>(fob + (size_t)m * D_ + cl) = o;
    }
}

// ---------------------------------------------------------------------------
// Tail part 1: enh = LN1(lerp(field) + x) -> bf16.
// ---------------------------------------------------------------------------
__global__ __launch_bounds__(256)
void k_enh(const float* __restrict__ x, const float* __restrict__ pos,
           const float* __restrict__ field, const float* __restrict__ g1,
           const float* __restrict__ b1, u16* __restrict__ enh)
{
    const int t = threadIdx.x;
    const int wid = t >> 6, l = t & 63;
    const int n = blockIdx.x * 4 + wid;
    const int b = blockIdx.y;
    const int c = l * 8;

    const float* xr = x + ((size_t)b * N_ + n) * D_ + c;
    float4 xa = *reinterpret_cast<const float4*>(xr);
    float4 xb = *reinterpret_cast<const float4*>(xr + 4);
    const float p = pos[(size_t)b * N_ + n];
    float u = p * (float)(M_ - 1);
    int i0 = (int)floorf(u);
    i0 = i0 < 0 ? 0 : (i0 > M_ - 2 ? M_ - 2 : i0);
    const float w = u - (float)i0;
    const float* fp0 = field + ((size_t)b * M_ + i0) * D_ + c;
    float4 f0a = *reinterpret_cast<const float4*>(fp0);
    float4 f0b = *reinterpret_cast<const float4*>(fp0 + 4);
    float4 f1a = *reinterpret_cast<const float4*>(fp0 + D_);
    float4 f1b = *reinterpret_cast<const float4*>(fp0 + D_ + 4);

    float s[8];
    s[0] = f0a.x + w * (f1a.x - f0a.x) + xa.x;
    s[1] = f0a.y + w * (f1a.y - f0a.y) + xa.y;
    s[2] = f0a.z + w * (f1a.z - f0a.z) + xa.z;
    s[3] = f0a.w + w * (f1a.w - f0a.w) + xa.w;
    s[4] = f0b.x + w * (f1b.x - f0b.x) + xb.x;
    s[5] = f0b.y + w * (f1b.y - f0b.y) + xb.y;
    s[6] = f0b.z + w * (f1b.z - f0b.z) + xb.z;
    s[7] = f0b.w + w * (f1b.w - f0b.w) + xb.w;

    float sum = 0.f, ss = 0.f;
#pragma unroll
    for (int j = 0; j < 8; ++j) { sum += s[j]; ss += s[j] * s[j]; }
#pragma unroll
    for (int off = 1; off <= 32; off <<= 1) {
        sum += __shfl_xor(sum, off);
        ss  += __shfl_xor(ss, off);
    }
    const float mu = sum * (1.f / 512.f);
    const float rs = rsqrtf(ss * (1.f / 512.f) - mu * mu + EPS_);

    float4 ga = *reinterpret_cast<const float4*>(g1 + c);
    float4 gb = *reinterpret_cast<const float4*>(g1 + c + 4);
    float4 ba = *reinterpret_cast<const float4*>(b1 + c);
    float4 bb = *reinterpret_cast<const float4*>(b1 + c + 4);
    float4 ea, eb;
    ea.x = (s[0] - mu) * rs * ga.x + ba.x;
    ea.y = (s[1] - mu) * rs * ga.y + ba.y;
    ea.z = (s[2] - mu) * rs * ga.z + ba.z;
    ea.w = (s[3] - mu) * rs * ga.w + ba.w;
    eb.x = (s[4] - mu) * rs * gb.x + bb.x;
    eb.y = (s[5] - mu) * rs * gb.y + bb.y;
    eb.z = (s[6] - mu) * rs * gb.z + bb.z;
    eb.w = (s[7] - mu) * rs * gb.w + bb.w;
    *reinterpret_cast<u16x8*>(enh + ((size_t)b * N_ + n) * D_ + c) = pack8(ea, eb);
}

// ---------------------------------------------------------------------------
// Tail part 2 (round-14 known-good): out = LN2(enh @ WoT + bo + enh).
// Single-buffer BK=64, 72KB dyn LDS, Cs[32][516] 2-pass epilogue.
// ---------------------------------------------------------------------------
__global__ __launch_bounds__(512, 4)
void k_gemm_ln(const u16* __restrict__ enh, const u16* __restrict__ WoT,
               const float* __restrict__ bo, const float* __restrict__ g2,
               const float* __restrict__ b2, float* __restrict__ out)
{
    extern __shared__ u16 smem[];            // 72 KB
    u16* As = smem;                          // [64][64] linear+src-swz (8 KB)
    u16* Bs = smem + 64 * 64;                // [512][64] linear+src-swz (64 KB)
    float* Cs = (float*)smem;                // [32][516] fp32, reused post-GEMM

    const int t = threadIdx.x;
    const int r0 = blockIdx.x * 64;          // row in flattened [B*N][D]
    const int l = t & 63, wid = t >> 6;
    const int wm = wid >> 2, wn = wid & 3;

    f32x4 acc[2][8];
#pragma unroll
    for (int i = 0; i < 2; ++i)
#pragma unroll
        for (int j = 0; j < 8; ++j) acc[i][j] = (f32x4){0.f, 0.f, 0.f, 0.f};

    // staging assignments (chunk = 8 bf16 = 16B)
    const int a_row = t >> 3, a_sch = t & 7;                  // A: 512 chunks
    const u16* a_src = enh + (size_t)(r0 + a_row) * D_ + (a_sch ^ (a_row & 7)) * 8;
    u16* a_dst = As + (size_t)wid * 512;                      // wave-uniform base

    const int fr = l & 15, fj = l >> 4;                       // frag coords

    for (int ks = 0; ks < 8; ++ks) {
        const int kk = ks * 64;
        __syncthreads();                     // prev compute done (tiles reusable)
        gload16(a_src + kk, a_dst);
#pragma unroll
        for (int i = 0; i < 8; ++i) {
            const int cid = t + i * 512;                      // B chunk id
            const int brow = cid >> 3, bsch = cid & 7;
            gload16(WoT + (size_t)brow * D_ + kk + ((bsch ^ (brow & 7)) * 8),
                    Bs + (size_t)wid * 512 + i * 4096);
        }
        __syncthreads();                     // loads landed (vmcnt0 at barrier)

#pragma unroll
        for (int kl = 0; kl < 2; ++kl) {     // two k-halves of 32
            const int cbase = kl * 4 + fj;   // chunk index 0..7
            const int ar0 = wm * 32 + fr, ar1 = ar0 + 16;
            bf16x8 a0 = *reinterpret_cast<const bf16x8*>(
                As + ar0 * 64 + ((cbase ^ (ar0 & 7)) * 8));
            bf16x8 a1 = *reinterpret_cast<const bf16x8*>(
                As + ar1 * 64 + ((cbase ^ (ar1 & 7)) * 8));
#pragma unroll
            for (int nf = 0; nf < 8; ++nf) {
                const int bcol = wn * 128 + nf * 16 + fr;
                bf16x8 bw = *reinterpret_cast<const bf16x8*>(
                    Bs + bcol * 64 + ((cbase ^ (bcol & 7)) * 8));
                acc[0][nf] = __builtin_amdgcn_mfma_f32_16x16x32_bf16(a0, bw, acc[0][nf], 0, 0, 0);
                acc[1][nf] = __builtin_amdgcn_mfma_f32_16x16x32_bf16(a1, bw, acc[1][nf], 0, 0, 0);
            }
        }
    }

#pragma unroll
    for (int mf = 0; mf < 2; ++mf) {
        __syncthreads();   // pass separation (protects Cs reuse vs B reads / prev pass)
        // scatter acc + bias into Cs; localrow = wm*16 + (l>>4)*4 + r
#pragma unroll
        for (int nf = 0; nf < 8; ++nf) {
            const int col = wn * 128 + nf * 16 + fr;
            const float boc = bo[col];
#pragma unroll
            for (int r = 0; r < 4; ++r)
                Cs[(wm * 16 + fj * 4 + r) * 516 + col] = acc[mf][nf][r] + boc;
        }
        __syncthreads();
        // row pass: wave wid owns localrows wid*4..+3; cols {l*4, 256+l*4}
#pragma unroll
        for (int i = 0; i < 4; ++i) {
            const int lr = wid * 4 + i;
            const int grow = r0 + (lr >> 4) * 32 + mf * 16 + (lr & 15);
            const int c1 = l * 4, c2 = 256 + l * 4;
            float4 fa = *reinterpret_cast<const float4*>(&Cs[lr * 516 + c1]);
            float4 fb4 = *reinterpret_cast<const float4*>(&Cs[lr * 516 + c2]);
            u16x4 e1 = *reinterpret_cast<const u16x4*>(enh + (size_t)grow * D_ + c1);
            u16x4 e2 = *reinterpret_cast<const u16x4*>(enh + (size_t)grow * D_ + c2);
            float v[8];
            v[0] = fa.x + bf2f(e1[0]); v[1] = fa.y + bf2f(e1[1]);
            v[2] = fa.z + bf2f(e1[2]); v[3] = fa.w + bf2f(e1[3]);
            v[4] = fb4.x + bf2f(e2[0]); v[5] = fb4.y + bf2f(e2[1]);
            v[6] = fb4.z + bf2f(e2[2]); v[7] = fb4.w + bf2f(e2[3]);

            float sum = 0.f, ss = 0.f;
#pragma unroll
            for (int j = 0; j < 8; ++j) { sum += v[j]; ss += v[j] * v[j]; }
#pragma unroll
            for (int off = 1; off <= 32; off <<= 1) {
                sum += __shfl_xor(sum, off);
                ss  += __shfl_xor(ss, off);
            }
            const float mu = sum * (1.f / 512.f);
            const float rs = rsqrtf(ss * (1.f / 512.f) - mu * mu + EPS_);

            float4 ga = *reinterpret_cast<const float4*>(g2 + c1);
            float4 gb = *reinterpret_cast<const float4*>(g2 + c2);
            float4 ba = *reinterpret_cast<const float4*>(b2 + c1);
            float4 bb = *reinterpret_cast<const float4*>(b2 + c2);
            float4 oa, ob;
            oa.x = (v[0] - mu) * rs * ga.x + ba.x;
            oa.y = (v[1] - mu) * rs * ga.y + ba.y;
            oa.z = (v[2] - mu) * rs * ga.z + ba.z;
            oa.w = (v[3] - mu) * rs * ga.w + ba.w;
            ob.x = (v[4] - mu) * rs * gb.x + bb.x;
            ob.y = (v[5] - mu) * rs * gb.y + bb.y;
            ob.z = (v[6] - mu) * rs * gb.z + bb.z;
            ob.w = (v[7] - mu) * rs * gb.w + bb.w;
            float* orow = out + (size_t)grow * D_;
            *reinterpret_cast<float4*>(orow + c1) = oa;
            *reinterpret_cast<float4*>(orow + c2) = ob;
        }
    }
}

extern "C" void kernel_launch(void* const* d_in, const int* in_sizes, int n_in,
                              void* d_out, int out_size, void* d_ws, size_t ws_size,
                              hipStream_t stream) {
    (void)in_sizes; (void)n_in; (void)out_size; (void)ws_size;
    const float* x   = (const float*)d_in[0];
    const float* pos = (const float*)d_in[1];
    const float* gp  = (const float*)d_in[2];
    const float* ls  = (const float*)d_in[3];
    const float* al  = (const float*)d_in[4];
    const float* Wi  = (const float*)d_in[5];
    const float* bi  = (const float*)d_in[6];
    const float* g1  = (const float*)d_in[7];
    const float* b1  = (const float*)d_in[8];
    const float* Wo  = (const float*)d_in[9];
    const float* bo  = (const float*)d_in[10];
    const float* g2  = (const float*)d_in[11];
    const float* b2  = (const float*)d_in[12];
    float* out = (float*)d_out;

    float* f0 = (float*)d_ws;                              // 8 MB fp32 field
    float* f1 = f0 + (size_t)B_ * M_ * D_;                 // 8 MB ping-pong
    u16* xT  = (u16*)(f1 + (size_t)B_ * M_ * D_);          // 32 MB bf16 x^T
    u16* WiT = xT + (size_t)B_ * D_ * N_;                  // 512 KB
    u16* WoT = WiT + (size_t)D_ * D_;                      // 512 KB
    u16* enh = xT;                                         // alias: xT dead after project
    u16* part = (u16*)d_out;                               // 16 MB bf16 partials in
                                                           // d_out (dead before k_gemm_ln)

    const int smGemm = 64 * 64 * 2 + 512 * 64 * 2;         // 73728 B (k_gemm_ln)
    const int smProj = 64 * 64 * 2 + 128 * 64 * 2;         // 24576 B (k_projgemm)
    const int smDiff = 16 * 520 * 2 + 256 * 64 * 2;        // 49408 B (k_diffuse)
    hipFuncSetAttribute(reinterpret_cast<const void*>(k_gemm_ln),
                        hipFuncAttributeMaxDynamicSharedMemorySize, smGemm);
    hipFuncSetAttribute(reinterpret_cast<const void*>(k_projgemm),
                        hipFuncAttributeMaxDynamicSharedMemorySize, smProj);
    hipFuncSetAttribute(reinterpret_cast<const void*>(k_diffuse),
                        hipFuncAttributeMaxDynamicSharedMemorySize, smDiff);

    k_prep_T<<<dim3(D_ / 64, N_ / 64, B_), 256, 0, stream>>>(x, xT, N_, D_);
    k_prep_T<<<dim3(D_ / 64, D_ / 64, 1), 256, 0, stream>>>(Wi, WiT, D_, D_);
    k_prep_T<<<dim3(D_ / 64, D_ / 64, 1), 256, 0, stream>>>(Wo, WoT, D_, D_);
    k_projgemm<<<dim3(1024), 512, smProj, stream>>>(pos, gp, ls, xT, part);
    k_sum<<<dim3((B_ * M_ * D_) / (256 * 8)), 256, 0, stream>>>(part, f0);
    k_diffuse<<<dim3(M_ / 16, D_ / 256, B_), 256, smDiff, stream>>>(f0, WiT, bi, al, f1);
    k_diffuse<<<dim3(M_ / 16, D_ / 256, B_), 256, smDiff, stream>>>(f1, WiT, bi, al, f0);
    k_diffuse<<<dim3(M_ / 16, D_ / 256, B_), 256, smDiff, stream>>>(f0, WiT, bi, al, f1);
    k_diffuse<<<dim3(M_ / 16, D_ / 256, B_), 256, smDiff, stream>>>(f1, WiT, bi, al, f0);
    k_enh<<<dim3(N_ / 4, B_), 256, 0, stream>>>(x, pos, f0, g1, b1, enh);
    k_gemm_ln<<<dim3(B_ * N_ / 64), 512, smGemm, stream>>>(enh, WoT, bo, g2, b2, out);
}

// Round 19
// 163.000 us; speedup vs baseline: 1.0661x; 1.0147x over previous
//
#include <hip/hip_runtime.h>
#include <cmath>

#define B_ 8
#define N_ 4096
#define D_ 512
#define M_ 512
#define EPS_ 1e-5f
#define DT_ 0.25f

typedef unsigned short u16;
typedef unsigned int u32;
typedef __attribute__((ext_vector_type(8))) u16 u16x8;
typedef __attribute__((ext_vector_type(4))) u16 u16x4;
typedef __attribute__((ext_vector_type(8))) short bf16x8;
typedef __attribute__((ext_vector_type(4))) float f32x4;

__device__ __forceinline__ float bf2f(u16 h) {
    return __builtin_bit_cast(float, (u32)h << 16);
}
// hardware packed fp32->bf16 (gfx950 v_cvt_pk_bf16_f32, RNE) [T12 recipe]
__device__ __forceinline__ u32 cvtpk(float lo, float hi) {
    u32 r;
    asm("v_cvt_pk_bf16_f32 %0, %1, %2" : "=v"(r) : "v"(lo), "v"(hi));
    return r;
}
__device__ __forceinline__ u16 f2bf(float f) { return (u16)cvtpk(f, 0.f); }
__device__ __forceinline__ u16x8 pack8(float4 a, float4 b) {
    union { u32 w[4]; u16x8 o; } u;
    u.w[0] = cvtpk(a.x, a.y); u.w[1] = cvtpk(a.z, a.w);
    u.w[2] = cvtpk(b.x, b.y); u.w[3] = cvtpk(b.z, b.w);
    return u.o;
}

// async global->LDS, 16B per lane; lds must be wave-uniform base (+lane*16 HW)
__device__ __forceinline__ void gload16(const void* g, void* l) {
    __builtin_amdgcn_global_load_lds(
        (const __attribute__((address_space(1))) void*)g,
        (__attribute__((address_space(3))) void*)l, 16, 0, 0);
}

// ---------------------------------------------------------------------------
// Transpose + fp32->bf16: src [Z][R][C] -> dst [Z][C][R]   (x -> xT)
// ---------------------------------------------------------------------------
__global__ __launch_bounds__(256)
void k_prep_T(const float* __restrict__ src, u16* __restrict__ dst, int R, int C)
{
    __shared__ float tile[64][65];
    const int t = threadIdx.x;
    const int c0 = blockIdx.x * 64;
    const int r0 = blockIdx.y * 64;
    const int z  = blockIdx.z;
    const float* s = src + (size_t)z * R * C;
    u16* d = dst + (size_t)z * R * C;
    const int rl = t >> 4, cc = (t & 15) * 4;
#pragma unroll
    for (int i = 0; i < 4; ++i) {
        float4 v = *reinterpret_cast<const float4*>(s + (size_t)(r0 + rl + i * 16) * C + c0 + cc);
        tile[rl + i * 16][cc + 0] = v.x;
        tile[rl + i * 16][cc + 1] = v.y;
        tile[rl + i * 16][cc + 2] = v.z;
        tile[rl + i * 16][cc + 3] = v.w;
    }
    __syncthreads();
#pragma unroll
    for (int i = 0; i < 2; ++i) {
        int q = t + i * 256;
        int cl = q >> 3, rc = (q & 7) * 8;
        float4 va, vb;
        va.x = tile[rc + 0][cl]; va.y = tile[rc + 1][cl];
        va.z = tile[rc + 2][cl]; va.w = tile[rc + 3][cl];
        vb.x = tile[rc + 4][cl]; vb.y = tile[rc + 5][cl];
        vb.z = tile[rc + 6][cl]; vb.w = tile[rc + 7][cl];
        *reinterpret_cast<u16x8*>(d + (size_t)(c0 + cl) * R + r0 + rc) = pack8(va, vb);
    }
}

// ---------------------------------------------------------------------------
// Weight transpose (both Wi and Wo in ONE launch): z selects the pair.
// 512x512 fp32 -> bf16 transposed.
// ---------------------------------------------------------------------------
__global__ __launch_bounds__(256)
void k_prep_W(const float* __restrict__ srcA, u16* __restrict__ dstA,
              const float* __restrict__ srcB, u16* __restrict__ dstB)
{
    __shared__ float tile[64][65];
    const int t = threadIdx.x;
    const int c0 = blockIdx.x * 64;
    const int r0 = blockIdx.y * 64;
    const float* s = (blockIdx.z == 0) ? srcA : srcB;
    u16* d        = (blockIdx.z == 0) ? dstA : dstB;
    const int rl = t >> 4, cc = (t & 15) * 4;
#pragma unroll
    for (int i = 0; i < 4; ++i) {
        float4 v = *reinterpret_cast<const float4*>(s + (size_t)(r0 + rl + i * 16) * D_ + c0 + cc);
        tile[rl + i * 16][cc + 0] = v.x;
        tile[rl + i * 16][cc + 1] = v.y;
        tile[rl + i * 16][cc + 2] = v.z;
        tile[rl + i * 16][cc + 3] = v.w;
    }
    __syncthreads();
#pragma unroll
    for (int i = 0; i < 2; ++i) {
        int q = t + i * 256;
        int cl = q >> 3, rc = (q & 7) * 8;
        float4 va, vb;
        va.x = tile[rc + 0][cl]; va.y = tile[rc + 1][cl];
        va.z = tile[rc + 2][cl]; va.w = tile[rc + 3][cl];
        vb.x = tile[rc + 4][cl]; vb.y = tile[rc + 5][cl];
        vb.z = tile[rc + 6][cl]; vb.w = tile[rc + 7][cl];
        *reinterpret_cast<u16x8*>(d + (size_t)(c0 + cl) * D_ + r0 + rc) = pack8(va, vb);
    }
}

// ---------------------------------------------------------------------------
// Projection GEMM, fused RBF A-tile (hw cvt_pk), tile 64x128, 24KB LDS,
// 4 blocks/CU, grid 1024 XCD-grouped. NO ATOMICS: each K-chunk writes its
// partial to part[kc][b][m][d] in BF16 (plain coalesced stores); k_sum reduces.
// ---------------------------------------------------------------------------
__global__ __launch_bounds__(512, 4)
void k_projgemm(const float* __restrict__ pos, const float* __restrict__ gp,
                const float* __restrict__ log_sigma, const u16* __restrict__ xT,
                u16* __restrict__ part)
{
    extern __shared__ u16 smem[];            // 24 KB
    u16* As = smem;                          // [64][64] kern tile (8 KB)
    u16* Bs = smem + 64 * 64;                // [128][64] xT rows (16 KB)

    const int t = threadIdx.x;
    // XCD-aware decode: all 32 blocks of a (b,chunk) group share d%8.
    const int d = blockIdx.x;                // 0..1023
    const int xcd = d & 7;
    const int q = d >> 3;                    // 0..127
    const int w = q & 31;                    // within-group: mtile + ntile
    const int mtile = w & 7;
    const int ntile = w >> 3;                // 0..3
    const int gq = q >> 5;                   // 0..3
    const int g = gq * 8 + xcd;              // group id 0..31
    const int b = g & 7;
    const int kc = g >> 3;                   // K-chunk 0..3
    const int m0 = mtile * 64;
    const int cb0 = ntile * 128;             // output col base
    const int nc0 = kc * 1024;               // K-chunk base

    const int l = t & 63, wid = t >> 6;
    const int wm = wid >> 2, wn = wid & 3;

    f32x4 acc[2][2];
#pragma unroll
    for (int i = 0; i < 2; ++i)
#pragma unroll
        for (int j = 0; j < 2; ++j) acc[i][j] = (f32x4){0.f, 0.f, 0.f, 0.f};

    // A-tile generation: thread owns (row=t>>3, LDS chunk=t&7) for global
    // n-chunk gch = sch ^ (row&7) (src-pre-swizzle).
    const int a_row = t >> 3, a_sch = t & 7;
    const int a_gch = a_sch ^ (a_row & 7);
    const float gm = gp[(size_t)b * M_ + m0 + a_row];
    const float sigma = __expf(log_sigma[0]);
    const float ninv2s2 = -0.5f / (sigma * sigma);
    const float* pb = pos + (size_t)b * N_ + nc0 + a_gch * 8;
    u16* a_wr = As + a_row * 64 + a_sch * 8;

    const u16* xb = xT + ((size_t)b * D_ + cb0) * N_ + nc0;

    const int fr = l & 15, fj = l >> 4;

    for (int ks = 0; ks < 16; ++ks) {
        const int kk = ks * 64;
        __syncthreads();                     // prev compute done
        // B stage: 128 rows x 64 k = 1024 chunks, 2/thread (async)
#pragma unroll
        for (int i = 0; i < 2; ++i) {
            const int cid = t + i * 512;
            const int brow = cid >> 3, bsch = cid & 7;
            gload16(xb + (size_t)brow * N_ + kk + ((bsch ^ (brow & 7)) * 8),
                    Bs + (size_t)wid * 512 + i * 4096);
        }
        // A compute: 8 RBF weights (hw cvt_pk), overlaps B flight
        {
            float4 p0 = *reinterpret_cast<const float4*>(pb + kk);
            float4 p1 = *reinterpret_cast<const float4*>(pb + kk + 4);
            float4 ea, eb;
            float d0 = gm - p0.x, d1 = gm - p0.y, d2 = gm - p0.z, d3 = gm - p0.w;
            float d4 = gm - p1.x, d5 = gm - p1.y, d6 = gm - p1.z, d7 = gm - p1.w;
            ea.x = __expf(d0 * d0 * ninv2s2); ea.y = __expf(d1 * d1 * ninv2s2);
            ea.z = __expf(d2 * d2 * ninv2s2); ea.w = __expf(d3 * d3 * ninv2s2);
            eb.x = __expf(d4 * d4 * ninv2s2); eb.y = __expf(d5 * d5 * ninv2s2);
            eb.z = __expf(d6 * d6 * ninv2s2); eb.w = __expf(d7 * d7 * ninv2s2);
            *reinterpret_cast<u16x8*>(a_wr) = pack8(ea, eb);
        }
        __syncthreads();                     // B landed + A ds_writes visible

#pragma unroll
        for (int kl = 0; kl < 2; ++kl) {
            const int cbase = kl * 4 + fj;
            const int ar0 = wm * 32 + fr, ar1 = ar0 + 16;
            bf16x8 a0 = *reinterpret_cast<const bf16x8*>(
                As + ar0 * 64 + ((cbase ^ (ar0 & 7)) * 8));
            bf16x8 a1 = *reinterpret_cast<const bf16x8*>(
                As + ar1 * 64 + ((cbase ^ (ar1 & 7)) * 8));
#pragma unroll
            for (int nf = 0; nf < 2; ++nf) {
                const int bcol = wn * 32 + nf * 16 + fr;
                bf16x8 bw = *reinterpret_cast<const bf16x8*>(
                    Bs + bcol * 64 + ((cbase ^ (bcol & 7)) * 8));
                acc[0][nf] = __builtin_amdgcn_mfma_f32_16x16x32_bf16(a0, bw, acc[0][nf], 0, 0, 0);
                acc[1][nf] = __builtin_amdgcn_mfma_f32_16x16x32_bf16(a1, bw, acc[1][nf], 0, 0, 0);
            }
        }
    }

    // plain coalesced bf16 stores of this K-chunk's partial (no RMW)
    u16* pb_out = part + ((size_t)(kc * B_ + b) * M_) * D_;
#pragma unroll
    for (int mf = 0; mf < 2; ++mf)
#pragma unroll
        for (int nf = 0; nf < 2; ++nf) {
            const int col = cb0 + wn * 32 + nf * 16 + fr;
#pragma unroll
            for (int r = 0; r < 4; ++r) {
                const int m = m0 + wm * 32 + mf * 16 + fj * 4 + r;
                pb_out[(size_t)m * D_ + col] = f2bf(acc[mf][nf][r]);
            }
        }
}

// ---------------------------------------------------------------------------
// Partial reduction: field = sum of 4 bf16 partials. 16MB read -> 8MB write.
// ---------------------------------------------------------------------------
__global__ __launch_bounds__(256)
void k_sum(const u16* __restrict__ part, float* __restrict__ field)
{
    const size_t i = ((size_t)blockIdx.x * 256 + threadIdx.x) * 8;
    const size_t S = (size_t)B_ * M_ * D_;
    u16x8 v0 = *reinterpret_cast<const u16x8*>(part + i);
    u16x8 v1 = *reinterpret_cast<const u16x8*>(part + S + i);
    u16x8 v2 = *reinterpret_cast<const u16x8*>(part + 2 * S + i);
    u16x8 v3 = *reinterpret_cast<const u16x8*>(part + 3 * S + i);
    float4 o1, o2;
    o1.x = (bf2f(v0[0]) + bf2f(v1[0])) + (bf2f(v2[0]) + bf2f(v3[0]));
    o1.y = (bf2f(v0[1]) + bf2f(v1[1])) + (bf2f(v2[1]) + bf2f(v3[1]));
    o1.z = (bf2f(v0[2]) + bf2f(v1[2])) + (bf2f(v2[2]) + bf2f(v3[2]));
    o1.w = (bf2f(v0[3]) + bf2f(v1[3])) + (bf2f(v2[3]) + bf2f(v3[3]));
    o2.x = (bf2f(v0[4]) + bf2f(v1[4])) + (bf2f(v2[4]) + bf2f(v3[4]));
    o2.y = (bf2f(v0[5]) + bf2f(v1[5])) + (bf2f(v2[5]) + bf2f(v3[5]));
    o2.z = (bf2f(v0[6]) + bf2f(v1[6])) + (bf2f(v2[6]) + bf2f(v3[6]));
    o2.w = (bf2f(v0[7]) + bf2f(v1[7])) + (bf2f(v2[7]) + bf2f(v3[7]));
    *reinterpret_cast<float4*>(field + i)     = o1;
    *reinterpret_cast<float4*>(field + i + 4) = o2;
}

// ---------------------------------------------------------------------------
// Diffusion step (round-14 known-good): fout = fin + dt*(alpha*lap + tanh(...)).
// WiT B-tiles staged per K-step via global_load_lds (BK=64, 8 steps,
// chunk^(row&7) src-pre-swizzle). fs (A) resident; Cs aliases Bs post-GEMM.
// grid (M/16, D/256, B), 256 thr, 49 KB dyn LDS -> 2 blocks/CU.
// ---------------------------------------------------------------------------
__global__ __launch_bounds__(256, 8)
void k_diffuse(const float* __restrict__ fin, const u16* __restrict__ WiT,
               const float* __restrict__ bi, const float* __restrict__ alpha_p,
               float* __restrict__ fout)
{
    extern __shared__ u16 dsm[];     // 49408 B
    u16* fs = dsm;                   // [16][520] bf16 field rows (16.6 KB)
    u16* Bs = dsm + 16 * 520;        // [256][64] WiT tile (32 KB)
    float* Cs = (float*)Bs;          // [16][260] fp32, aliases Bs post-GEMM

    const int t = threadIdx.x;
    const int m0 = blockIdx.x * 16;
    const int cb0 = blockIdx.y * 256;
    const int b = blockIdx.z;
    const int l = t & 63, wn = t >> 6;
    const int fr = l & 15, fj = l >> 4;
    const float* fb = fin + (size_t)b * M_ * D_;

    {   // stage fs: 16 rows x 512 cols fp32 -> bf16 (hw cvt)
        const int row = t >> 4, ch = (t & 15) * 32;
        const float* src = fb + (size_t)(m0 + row) * D_ + ch;
#pragma unroll
        for (int j = 0; j < 4; ++j) {
            float4 v0 = *reinterpret_cast<const float4*>(src + j * 8);
            float4 v1 = *reinterpret_cast<const float4*>(src + j * 8 + 4);
            *reinterpret_cast<u16x8*>(fs + row * 520 + ch + j * 8) = pack8(v0, v1);
        }
    }

    f32x4 acc[4];
#pragma unroll
    for (int i = 0; i < 4; ++i) acc[i] = (f32x4){0.f, 0.f, 0.f, 0.f};

    const u16* wb = WiT + (size_t)cb0 * D_;

    for (int ks = 0; ks < 8; ++ks) {
        const int kk = ks * 64;
        __syncthreads();                 // iter0: fs writes flushed; else: prev Bs reads done
        // stage B: 256 rows (Wi output-cols) x 64 k, 2048 chunks, 8/thread
#pragma unroll
        for (int i = 0; i < 8; ++i) {
            const int cid = t + i * 256;
            const int brow = cid >> 3, bsch = cid & 7;
            gload16(wb + (size_t)brow * D_ + kk + ((bsch ^ (brow & 7)) * 8),
                    Bs + (i * 256 + wn * 64) * 8);
        }
        __syncthreads();                 // loads landed

#pragma unroll
        for (int kl = 0; kl < 2; ++kl) {
            const int cbase = kl * 4 + fj;
            bf16x8 a = *reinterpret_cast<const bf16x8*>(
                fs + fr * 520 + kk + kl * 32 + fj * 8);
#pragma unroll
            for (int nf = 0; nf < 4; ++nf) {
                const int bcol = wn * 64 + nf * 16 + fr;
                bf16x8 bw = *reinterpret_cast<const bf16x8*>(
                    Bs + bcol * 64 + ((cbase ^ (bcol & 7)) * 8));
                acc[nf] = __builtin_amdgcn_mfma_f32_16x16x32_bf16(a, bw, acc[nf], 0, 0, 0);
            }
        }
    }

    __syncthreads();   // all Bs reads done before Cs (alias) overwrite
    // stage gemm+bias into Cs (scatter, conflict-free by 260 stride)
#pragma unroll
    for (int nf = 0; nf < 4; ++nf) {
        const int cl = wn * 64 + nf * 16 + fr;
        const float bic = bi[cb0 + cl];
#pragma unroll
        for (int r = 0; r < 4; ++r)
            Cs[(fj * 4 + r) * 260 + cl] = acc[nf][r] + bic;
    }
    __syncthreads();

    // row pass: wave wn owns rows wn*4..+3, fully vectorized
    const float al = alpha_p[0];
    float* fob = fout + (size_t)b * M_ * D_;
#pragma unroll
    for (int i = 0; i < 4; ++i) {
        const int row = wn * 4 + i;
        const int m = m0 + row;
        const int mu_ = m > 0 ? m - 1 : 0;
        const int md = m < M_ - 1 ? m + 1 : M_ - 1;
        const int cl = cb0 + l * 4;
        float4 g  = *reinterpret_cast<const float4*>(&Cs[row * 260 + l * 4]);
        float4 fc = *reinterpret_cast<const float4*>(fb + (size_t)m * D_ + cl);
        float4 fu = *reinterpret_cast<const float4*>(fb + (size_t)mu_ * D_ + cl);
        float4 fd = *reinterpret_cast<const float4*>(fb + (size_t)md * D_ + cl);
        float4 o;
        o.x = fc.x + DT_ * (al * (fu.x + fd.x - 2.f * fc.x) + tanhf(g.x));
        o.y = fc.y + DT_ * (al * (fu.y + fd.y - 2.f * fc.y) + tanhf(g.y));
        o.z = fc.z + DT_ * (al * (fu.z + fd.z - 2.f * fc.z) + tanhf(g.z));
        o.w = fc.w + DT_ * (al * (fu.w + fd.w - 2.f * fc.w) + tanhf(g.w));
        *reinterpret_cast<float4*>(fob + (size_t)m * D_ + cl) = o;
    }
}

// ---------------------------------------------------------------------------
// Tail part 1: enh = LN1(lerp(field) + x) -> bf16.
// ---------------------------------------------------------------------------
__global__ __launch_bounds__(256)
void k_enh(const float* __restrict__ x, const float* __restrict__ pos,
           const float* __restrict__ field, const float* __restrict__ g1,
           const float* __restrict__ b1, u16* __restrict__ enh)
{
    const int t = threadIdx.x;
    const int wid = t >> 6, l = t & 63;
    const int n = blockIdx.x * 4 + wid;
    const int b = blockIdx.y;
    const int c = l * 8;

    const float* xr = x + ((size_t)b * N_ + n) * D_ + c;
    float4 xa = *reinterpret_cast<const float4*>(xr);
    float4 xb = *reinterpret_cast<const float4*>(xr + 4);
    const float p = pos[(size_t)b * N_ + n];
    float u = p * (float)(M_ - 1);
    int i0 = (int)floorf(u);
    i0 = i0 < 0 ? 0 : (i0 > M_ - 2 ? M_ - 2 : i0);
    const float w = u - (float)i0;
    const float* fp0 = field + ((size_t)b * M_ + i0) * D_ + c;
    float4 f0a = *reinterpret_cast<const float4*>(fp0);
    float4 f0b = *reinterpret_cast<const float4*>(fp0 + 4);
    float4 f1a = *reinterpret_cast<const float4*>(fp0 + D_);
    float4 f1b = *reinterpret_cast<const float4*>(fp0 + D_ + 4);

    float s[8];
    s[0] = f0a.x + w * (f1a.x - f0a.x) + xa.x;
    s[1] = f0a.y + w * (f1a.y - f0a.y) + xa.y;
    s[2] = f0a.z + w * (f1a.z - f0a.z) + xa.z;
    s[3] = f0a.w + w * (f1a.w - f0a.w) + xa.w;
    s[4] = f0b.x + w * (f1b.x - f0b.x) + xb.x;
    s[5] = f0b.y + w * (f1b.y - f0b.y) + xb.y;
    s[6] = f0b.z + w * (f1b.z - f0b.z) + xb.z;
    s[7] = f0b.w + w * (f1b.w - f0b.w) + xb.w;

    float sum = 0.f, ss = 0.f;
#pragma unroll
    for (int j = 0; j < 8; ++j) { sum += s[j]; ss += s[j] * s[j]; }
#pragma unroll
    for (int off = 1; off <= 32; off <<= 1) {
        sum += __shfl_xor(sum, off);
        ss  += __shfl_xor(ss, off);
    }
    const float mu = sum * (1.f / 512.f);
    const float rs = rsqrtf(ss * (1.f / 512.f) - mu * mu + EPS_);

    float4 ga = *reinterpret_cast<const float4*>(g1 + c);
    float4 gb = *reinterpret_cast<const float4*>(g1 + c + 4);
    float4 ba = *reinterpret_cast<const float4*>(b1 + c);
    float4 bb = *reinterpret_cast<const float4*>(b1 + c + 4);
    float4 ea, eb;
    ea.x = (s[0] - mu) * rs * ga.x + ba.x;
    ea.y = (s[1] - mu) * rs * ga.y + ba.y;
    ea.z = (s[2] - mu) * rs * ga.z + ba.z;
    ea.w = (s[3] - mu) * rs * ga.w + ba.w;
    eb.x = (s[4] - mu) * rs * gb.x + bb.x;
    eb.y = (s[5] - mu) * rs * gb.y + bb.y;
    eb.z = (s[6] - mu) * rs * gb.z + bb.z;
    eb.w = (s[7] - mu) * rs * gb.w + bb.w;
    *reinterpret_cast<u16x8*>(enh + ((size_t)b * N_ + n) * D_ + c) = pack8(ea, eb);
}

// ---------------------------------------------------------------------------
// Tail part 2 (round-14 known-good): out = LN2(enh @ WoT + bo + enh).
// Single-buffer BK=64, 72KB dyn LDS, Cs[32][516] 2-pass epilogue.
// ---------------------------------------------------------------------------
__global__ __launch_bounds__(512, 4)
void k_gemm_ln(const u16* __restrict__ enh, const u16* __restrict__ WoT,
               const float* __restrict__ bo, const float* __restrict__ g2,
               const float* __restrict__ b2, float* __restrict__ out)
{
    extern __shared__ u16 smem[];            // 72 KB
    u16* As = smem;                          // [64][64] linear+src-swz (8 KB)
    u16* Bs = smem + 64 * 64;                // [512][64] linear+src-swz (64 KB)
    float* Cs = (float*)smem;                // [32][516] fp32, reused post-GEMM

    const int t = threadIdx.x;
    const int r0 = blockIdx.x * 64;          // row in flattened [B*N][D]
    const int l = t & 63, wid = t >> 6;
    const int wm = wid >> 2, wn = wid & 3;

    f32x4 acc[2][8];
#pragma unroll
    for (int i = 0; i < 2; ++i)
#pragma unroll
        for (int j = 0; j < 8; ++j) acc[i][j] = (f32x4){0.f, 0.f, 0.f, 0.f};

    // staging assignments (chunk = 8 bf16 = 16B)
    const int a_row = t >> 3, a_sch = t & 7;                  // A: 512 chunks
    const u16* a_src = enh + (size_t)(r0 + a_row) * D_ + (a_sch ^ (a_row & 7)) * 8;
    u16* a_dst = As + (size_t)wid * 512;                      // wave-uniform base

    const int fr = l & 15, fj = l >> 4;                       // frag coords

    for (int ks = 0; ks < 8; ++ks) {
        const int kk = ks * 64;
        __syncthreads();                     // prev compute done (tiles reusable)
        gload16(a_src + kk, a_dst);
#pragma unroll
        for (int i = 0; i < 8; ++i) {
            const int cid = t + i * 512;                      // B chunk id
            const int brow = cid >> 3, bsch = cid & 7;
            gload16(WoT + (size_t)brow * D_ + kk + ((bsch ^ (brow & 7)) * 8),
                    Bs + (size_t)wid * 512 + i * 4096);
        }
        __syncthreads();                     // loads landed (vmcnt0 at barrier)

#pragma unroll
        for (int kl = 0; kl < 2; ++kl) {     // two k-halves of 32
            const int cbase = kl * 4 + fj;   // chunk index 0..7
            const int ar0 = wm * 32 + fr, ar1 = ar0 + 16;
            bf16x8 a0 = *reinterpret_cast<const bf16x8*>(
                As + ar0 * 64 + ((cbase ^ (ar0 & 7)) * 8));
            bf16x8 a1 = *reinterpret_cast<const bf16x8*>(
                As + ar1 * 64 + ((cbase ^ (ar1 & 7)) * 8));
#pragma unroll
            for (int nf = 0; nf < 8; ++nf) {
                const int bcol = wn * 128 + nf * 16 + fr;
                bf16x8 bw = *reinterpret_cast<const bf16x8*>(
                    Bs + bcol * 64 + ((cbase ^ (bcol & 7)) * 8));
                acc[0][nf] = __builtin_amdgcn_mfma_f32_16x16x32_bf16(a0, bw, acc[0][nf], 0, 0, 0);
                acc[1][nf] = __builtin_amdgcn_mfma_f32_16x16x32_bf16(a1, bw, acc[1][nf], 0, 0, 0);
            }
        }
    }

#pragma unroll
    for (int mf = 0; mf < 2; ++mf) {
        __syncthreads();   // pass separation (protects Cs reuse vs B reads / prev pass)
        // scatter acc + bias into Cs; localrow = wm*16 + (l>>4)*4 + r
#pragma unroll
        for (int nf = 0; nf < 8; ++nf) {
            const int col = wn * 128 + nf * 16 + fr;
            const float boc = bo[col];
#pragma unroll
            for (int r = 0; r < 4; ++r)
                Cs[(wm * 16 + fj * 4 + r) * 516 + col] = acc[mf][nf][r] + boc;
        }
        __syncthreads();
        // row pass: wave wid owns localrows wid*4..+3; cols {l*4, 256+l*4}
#pragma unroll
        for (int i = 0; i < 4; ++i) {
            const int lr = wid * 4 + i;
            const int grow = r0 + (lr >> 4) * 32 + mf * 16 + (lr & 15);
            const int c1 = l * 4, c2 = 256 + l * 4;
            float4 fa = *reinterpret_cast<const float4*>(&Cs[lr * 516 + c1]);
            float4 fb4 = *reinterpret_cast<const float4*>(&Cs[lr * 516 + c2]);
            u16x4 e1 = *reinterpret_cast<const u16x4*>(enh + (size_t)grow * D_ + c1);
            u16x4 e2 = *reinterpret_cast<const u16x4*>(enh + (size_t)grow * D_ + c2);
            float v[8];
            v[0] = fa.x + bf2f(e1[0]); v[1] = fa.y + bf2f(e1[1]);
            v[2] = fa.z + bf2f(e1[2]); v[3] = fa.w + bf2f(e1[3]);
            v[4] = fb4.x + bf2f(e2[0]); v[5] = fb4.y + bf2f(e2[1]);
            v[6] = fb4.z + bf2f(e2[2]); v[7] = fb4.w + bf2f(e2[3]);

            float sum = 0.f, ss = 0.f;
#pragma unroll
            for (int j = 0; j < 8; ++j) { sum += v[j]; ss += v[j] * v[j]; }
#pragma unroll
            for (int off = 1; off <= 32; off <<= 1) {
                sum += __shfl_xor(sum, off);
                ss  += __shfl_xor(ss, off);
            }
            const float mu = sum * (1.f / 512.f);
            const float rs = rsqrtf(ss * (1.f / 512.f) - mu * mu + EPS_);

            float4 ga = *reinterpret_cast<const float4*>(g2 + c1);
            float4 gb = *reinterpret_cast<const float4*>(g2 + c2);
            float4 ba = *reinterpret_cast<const float4*>(b2 + c1);
            float4 bb = *reinterpret_cast<const float4*>(b2 + c2);
            float4 oa, ob;
            oa.x = (v[0] - mu) * rs * ga.x + ba.x;
            oa.y = (v[1] - mu) * rs * ga.y + ba.y;
            oa.z = (v[2] - mu) * rs * ga.z + ba.z;
            oa.w = (v[3] - mu) * rs * ga.w + ba.w;
            ob.x = (v[4] - mu) * rs * gb.x + bb.x;
            ob.y = (v[5] - mu) * rs * gb.y + bb.y;
            ob.z = (v[6] - mu) * rs * gb.z + bb.z;
            ob.w = (v[7] - mu) * rs * gb.w + bb.w;
            float* orow = out + (size_t)grow * D_;
            *reinterpret_cast<float4*>(orow + c1) = oa;
            *reinterpret_cast<float4*>(orow + c2) = ob;
        }
    }
}

extern "C" void kernel_launch(void* const* d_in, const int* in_sizes, int n_in,
                              void* d_out, int out_size, void* d_ws, size_t ws_size,
                              hipStream_t stream) {
    (void)in_sizes; (void)n_in; (void)out_size; (void)ws_size;
    const float* x   = (const float*)d_in[0];
    const float* pos = (const float*)d_in[1];
    const float* gp  = (const float*)d_in[2];
    const float* ls  = (const float*)d_in[3];
    const float* al  = (const float*)d_in[4];
    const float* Wi  = (const float*)d_in[5];
    const float* bi  = (const float*)d_in[6];
    const float* g1  = (const float*)d_in[7];
    const float* b1  = (const float*)d_in[8];
    const float* Wo  = (const float*)d_in[9];
    const float* bo  = (const float*)d_in[10];
    const float* g2  = (const float*)d_in[11];
    const float* b2  = (const float*)d_in[12];
    float* out = (float*)d_out;

    float* f0 = (float*)d_ws;                              // 8 MB fp32 field
    float* f1 = f0 + (size_t)B_ * M_ * D_;                 // 8 MB ping-pong
    u16* xT  = (u16*)(f1 + (size_t)B_ * M_ * D_);          // 32 MB bf16 x^T
    u16* WiT = xT + (size_t)B_ * D_ * N_;                  // 512 KB
    u16* WoT = WiT + (size_t)D_ * D_;                      // 512 KB
    u16* enh = xT;                                         // alias: xT dead after project
    u16* part = (u16*)d_out;                               // 16 MB bf16 partials in
                                                           // d_out (dead before k_gemm_ln)

    const int smGemm = 64 * 64 * 2 + 512 * 64 * 2;         // 73728 B (k_gemm_ln)
    const int smProj = 64 * 64 * 2 + 128 * 64 * 2;         // 24576 B (k_projgemm)
    const int smDiff = 16 * 520 * 2 + 256 * 64 * 2;        // 49408 B (k_diffuse)
    hipFuncSetAttribute(reinterpret_cast<const void*>(k_gemm_ln),
                        hipFuncAttributeMaxDynamicSharedMemorySize, smGemm);
    hipFuncSetAttribute(reinterpret_cast<const void*>(k_projgemm),
                        hipFuncAttributeMaxDynamicSharedMemorySize, smProj);
    hipFuncSetAttribute(reinterpret_cast<const void*>(k_diffuse),
                        hipFuncAttributeMaxDynamicSharedMemorySize, smDiff);

    k_prep_T<<<dim3(D_ / 64, N_ / 64, B_), 256, 0, stream>>>(x, xT, N_, D_);
    k_prep_W<<<dim3(D_ / 64, D_ / 64, 2), 256, 0, stream>>>(Wi, WiT, Wo, WoT);
    k_projgemm<<<dim3(1024), 512, smProj, stream>>>(pos, gp, ls, xT, part);
    k_sum<<<dim3((B_ * M_ * D_) / (256 * 8)), 256, 0, stream>>>(part, f0);
    k_diffuse<<<dim3(M_ / 16, D_ / 256, B_), 256, smDiff, stream>>>(f0, WiT, bi, al, f1);
    k_diffuse<<<dim3(M_ / 16, D_ / 256, B_), 256, smDiff, stream>>>(f1, WiT, bi, al, f0);
    k_diffuse<<<dim3(M_ / 16, D_ / 256, B_), 256, smDiff, stream>>>(f0, WiT, bi, al, f1);
    k_diffuse<<<dim3(M_ / 16, D_ / 256, B_), 256, smDiff, stream>>>(f1, WiT, bi, al, f0);
    k_enh<<<dim3(N_ / 4, B_), 256, 0, stream>>>(x, pos, f0, g1, b1, enh);
    k_gemm_ln<<<dim3(B_ * N_ / 64), 512, smGemm, stream>>>(enh, WoT, bo, g2, b2, out);
}